// Round 9
// baseline (376.078 us; speedup 1.0000x reference)
//
#include <hip/hip_runtime.h>

#define D_MODEL 2048
#define GHD 512        // NUM_KV_GROUPS * HEAD_DIM
#define HD 128
#define NQH 16
#define B_SZ 2
#define SEQ 2048
#define M_TOT (B_SZ * SEQ)   // 4096

typedef _Float16 f16;
typedef _Float16 f16x4 __attribute__((ext_vector_type(4)));
typedef _Float16 f16x8 __attribute__((ext_vector_type(8)));
typedef float f32x4 __attribute__((ext_vector_type(4)));

typedef const __attribute__((address_space(1))) void gvoid;
typedef __attribute__((address_space(3))) void lvoid;
typedef __attribute__((address_space(3))) f16 lf16;

// raw barrier (no vmcnt(0) drain) with compiler fences
#define BAR() do { asm volatile("" ::: "memory"); \
                   __builtin_amdgcn_s_barrier();  \
                   asm volatile("" ::: "memory"); } while (0)
#define WAIT_VM8() asm volatile("s_waitcnt vmcnt(8)" ::: "memory")
#define WAIT_VM0() asm volatile("s_waitcnt vmcnt(0)" ::: "memory")
#define WAIT_LGKM(N) do { asm volatile("s_waitcnt lgkmcnt(" #N ")" ::: "memory"); \
                          __builtin_amdgcn_sched_barrier(0); } while (0)

// hardware transpose read: with per-lane addr = base + l*8B, lane l elem j
// reads f16 at base_f16[OFF/2 + (l>>4)*64 + j*16 + (l&15)]
template<int OFF>
__device__ __forceinline__ f16x4 tr16(unsigned a) {
    f16x4 d;
    asm volatile("ds_read_b64_tr_b16 %0, %1 offset:%2"
                 : "=v"(d) : "v"(a), "i"(OFF));
    return d;
}

// ---------------------------------------------------------------------------
// x (fp32) -> hi/lo f16 split, elementwise
// ---------------------------------------------------------------------------
__global__ __launch_bounds__(256) void split_f32(
    const float* __restrict__ X, f16* __restrict__ Xh, f16* __restrict__ Xl)
{
    const size_t i = ((size_t)blockIdx.x * 256 + threadIdx.x) * 8;
    const float4 v0 = *(const float4*)(X + i);
    const float4 v1 = *(const float4*)(X + i + 4);
    const float a[8] = {v0.x, v0.y, v0.z, v0.w, v1.x, v1.y, v1.z, v1.w};
    f16x8 h, lo;
#pragma unroll
    for (int e = 0; e < 8; ++e) {
        h[e] = (f16)a[e];
        lo[e] = (f16)(a[e] - (float)h[e]);
    }
    *(f16x8*)(Xh + i) = h;
    *(f16x8*)(Xl + i) = lo;
}

// ---------------------------------------------------------------------------
// Transpose + f16 cast: W[K][N] fp32 -> Th[(row_off+n)][K] f16
// ---------------------------------------------------------------------------
__global__ __launch_bounds__(256) void transpose_cast(
    const float* __restrict__ W, f16* __restrict__ Th,
    int K, int N, int row_off)
{
    __shared__ float Ls[32][33];
    const int t = threadIdx.x;
    const int n0 = blockIdx.x << 5, k0 = blockIdx.y << 5;
    {
        const int kr = t >> 3, nq = (t & 7) << 2;
        const float4 v = *(const float4*)&W[(size_t)(k0 + kr) * N + n0 + nq];
        Ls[kr][nq + 0] = v.x; Ls[kr][nq + 1] = v.y;
        Ls[kr][nq + 2] = v.z; Ls[kr][nq + 3] = v.w;
    }
    __syncthreads();
    const int nr = t >> 3, kq = (t & 7) << 2;
    f16x4 hv;
#pragma unroll
    for (int e = 0; e < 4; ++e) hv[e] = (f16)Ls[kq + e][nr];
    *(f16x4*)&Th[(size_t)(row_off + n0 + nr) * K + k0 + kq] = hv;
}

// ---------------------------------------------------------------------------
// 2-term split-precision MFMA GEMM: C = (Ah+Al) @ Bh^T + bias
// BM=128, BK=32, 256 threads (4 waves). XCD-aware block swizzle (T1).
// ---------------------------------------------------------------------------
template<int BN, bool OUT32>
__global__ __launch_bounds__(256) void gemm_split(
    const f16* __restrict__ Agh, const f16* __restrict__ Agl,
    const f16* __restrict__ BTh,
    const float* __restrict__ bias0, const float* __restrict__ bias1,
    void* __restrict__ C0v, void* __restrict__ C1v,
    int Nsplit, int ld0, int ld1, int K, float outscale)
{
    constexpr int WN = BN / 64;
    constexpr int WM = 4 / WN;
    constexpr int WI = 128 / (WM * 16);
    constexpr int LDK = 40;
    constexpr int NB = (BN * 4) / 256;

    __shared__ f16 Ah[128 * LDK], Al[128 * LDK];
    __shared__ f16 Bh[BN * LDK];

    const int tid = threadIdx.x;
    const int l = tid & 63, w = tid >> 6;
    const int l15 = l & 15, lq = l >> 4;
    const int wr = w / WN, wc = w % WN;

    // XCD swizzle: contiguous chunk of tiles per XCD
    const int nwgx = gridDim.x;
    const int orig = blockIdx.y * nwgx + blockIdx.x;
    const int cpx = (nwgx * gridDim.y) >> 3;
    const int sw = (orig & 7) * cpx + (orig >> 3);
    const int m0 = (sw / nwgx) << 7;
    const int n0 = (sw % nwgx) * BN;

    f32x4 acc[WI][4];
#pragma unroll
    for (int i = 0; i < WI; ++i)
#pragma unroll
        for (int j = 0; j < 4; ++j) acc[i][j] = (f32x4){0.f, 0.f, 0.f, 0.f};

    const int ar  = tid >> 2;
    const int auk = (tid & 3) << 3;
    const f16* Ahp = Agh + (size_t)(m0 + ar) * K + auk;
    const f16* Alp = Agl + (size_t)(m0 + ar) * K + auk;
    const int bnr = tid >> 2, buk = (tid & 3) << 3;
    const f16* Bhp = BTh + (size_t)(n0 + bnr) * K + buk;

    f16x8 a0h = *(const f16x8*)(Ahp);
    f16x8 a1h = *(const f16x8*)(Ahp + (size_t)64 * K);
    f16x8 a0l = *(const f16x8*)(Alp);
    f16x8 a1l = *(const f16x8*)(Alp + (size_t)64 * K);
    f16x8 bhv[NB];
#pragma unroll
    for (int it = 0; it < NB; ++it)
        bhv[it] = *(const f16x8*)(Bhp + (size_t)(it * 64) * K);

    for (int k0 = 0; k0 < K; k0 += 32) {
        __syncthreads();
        *(f16x8*)&Ah[ar * LDK + auk] = a0h;
        *(f16x8*)&Ah[(ar + 64) * LDK + auk] = a1h;
        *(f16x8*)&Al[ar * LDK + auk] = a0l;
        *(f16x8*)&Al[(ar + 64) * LDK + auk] = a1l;
#pragma unroll
        for (int it = 0; it < NB; ++it)
            *(f16x8*)&Bh[(bnr + it * 64) * LDK + buk] = bhv[it];
        __syncthreads();

        // prefetch next k0 (flies under MFMA; last-iter over-read stays in ws)
        const int kn = k0 + 32;
        a0h = *(const f16x8*)(Ahp + kn);
        a1h = *(const f16x8*)(Ahp + (size_t)64 * K + kn);
        a0l = *(const f16x8*)(Alp + kn);
        a1l = *(const f16x8*)(Alp + (size_t)64 * K + kn);
#pragma unroll
        for (int it = 0; it < NB; ++it)
            bhv[it] = *(const f16x8*)(Bhp + (size_t)(it * 64) * K + kn);

        f16x8 afh[WI], afl[WI];
#pragma unroll
        for (int i = 0; i < WI; ++i) {
            const int row = wr * (WI * 16) + i * 16 + l15;
            afh[i] = *(const f16x8*)&Ah[row * LDK + lq * 8];
            afl[i] = *(const f16x8*)&Al[row * LDK + lq * 8];
        }
#pragma unroll
        for (int j = 0; j < 4; ++j) {
            const int bn = wc * 64 + j * 16 + l15;
            const f16x8 bfh = *(const f16x8*)&Bh[bn * LDK + lq * 8];
#pragma unroll
            for (int i = 0; i < WI; ++i)
                acc[i][j] = __builtin_amdgcn_mfma_f32_16x16x32_f16(afh[i], bfh, acc[i][j], 0, 0, 0);
#pragma unroll
            for (int i = 0; i < WI; ++i)
                acc[i][j] = __builtin_amdgcn_mfma_f32_16x16x32_f16(afl[i], bfh, acc[i][j], 0, 0, 0);
        }
    }

#pragma unroll
    for (int j = 0; j < 4; ++j) {
        const int ng = n0 + wc * 64 + j * 16 + l15;
        const bool first = ng < Nsplit;
        const float bvf = first ? bias0[ng] : bias1[ng - Nsplit];
        const int nc = first ? ng : ng - Nsplit;
        const int ldc = first ? ld0 : ld1;
#pragma unroll
        for (int i = 0; i < WI; ++i) {
            const int mg = m0 + wr * (WI * 16) + i * 16 + lq * 4;
#pragma unroll
            for (int r = 0; r < 4; ++r) {
                const float v = (acc[i][j][r] + bvf) * outscale;
                if (OUT32)
                    ((float*)(first ? C0v : C1v))[(size_t)(mg + r) * ldc + nc] = v;
                else
                    ((f16*)(first ? C0v : C1v))[(size_t)(mg + r) * ldc + nc] = (f16)v;
            }
        }
    }
}

#define SHUF8(x, y) __builtin_shufflevector(x, y, 0, 1, 2, 3, 4, 5, 6, 7)

// ---------------------------------------------------------------------------
// fp16-MFMA flash attention v5: 4 waves x 64 q-rows (QBLK=256, rg=4), KV
// tile 64. Each K/V LDS fragment now feeds 4 MFMAs -> DS ops per MFMA halved
// vs v4 (the CU-shared DS pipe was the 64%-busy limiter). 1 block/CU,
// 1 wave/SIMD, ~300 VGPR (launch_bounds(256,1)). Everything else kept:
// double-buffered K/V via global_load_lds + counted vmcnt + raw barriers,
// tr16 V and tr16 P, per-db lgkmcnt-pipelined PV, exp2-direct group-max-defer
// softmax, hi/lo f16 output.
// ---------------------------------------------------------------------------
__global__ __launch_bounds__(256, 1) void flash_attn_mfma(
    const f16* __restrict__ Q, const f16* __restrict__ Kp,
    const f16* __restrict__ Vp, f16* __restrict__ AOh, f16* __restrict__ AOl)
{
    __shared__ f16 KsA[2][64 * 128];   // 32 KB
    __shared__ f16 VtA[2][64 * 128];   // 32 KB (tr16 subtiled)
    __shared__ f16 Pt[4][4096];        // 32 KB per-wave transposed P (64 q x 64 kv)

    const int tid = threadIdx.x;
    const int w = tid >> 6, l = tid & 63;
    const int l15 = l & 15, lq = l >> 4;
    const int b = blockIdx.z, h = blockIdx.y, g = h >> 2;
    const int q0 = blockIdx.x << 8;    // 256 q-rows per block

    const f16* Qb = Q + (size_t)(b * SEQ + q0) * D_MODEL + h * HD;
    const f16* Kb = Kp + (size_t)b * SEQ * GHD + g * HD;
    const f16* Vb = Vp + (size_t)b * SEQ * GHD + g * HD;

    // Q fragments: wave owns rows [w*64, w*64+64) as 4 groups of 16
    f16x8 aq[4][4];
#pragma unroll
    for (int rg = 0; rg < 4; ++rg) {
        const f16* qrow = Qb + (size_t)(w * 64 + rg * 16 + l15) * D_MODEL;
#pragma unroll
        for (int c = 0; c < 4; ++c)
            aq[rg][c] = *(const f16x8*)(qrow + c * 32 + lq * 8);
    }

    // staging addresses (per-lane-permuted global source, linear LDS dest)
    lf16* Ks3 = (lf16*)&KsA[0][0];
    lf16* Vt3 = (lf16*)&VtA[0][0];
    const f16* ksrc[4]; lf16* kdst[4];
    const f16* vsrc[4]; lf16* vdst[4];
#pragma unroll
    for (int i = 0; i < 4; ++i) {
        const int s = tid + (i << 8);
        {
            const int row = s >> 4, ul = s & 15;
            ksrc[i] = Kb + (size_t)row * GHD + ((ul ^ (row & 7)) << 3);
            kdst[i] = Ks3 + s * 8;
        }
        {
            const int dbit = s & 1, kvlo = (s >> 1) & 3, vlq = (s >> 3) & 3;
            const int jh = (s >> 5) & 1, kc = (s >> 6) & 1, dsub = s >> 7;
            const int kv = (kc << 5) | (vlq << 3) | (jh << 2) | kvlo;
            vsrc[i] = Vb + (size_t)kv * GHD + ((dsub << 4) | (dbit << 3));
            vdst[i] = Vt3 + s * 8;
        }
    }
    const unsigned vta0 = (unsigned)(size_t)(Vt3 + l * 4);
    const unsigned vta1 = vta0 + 16384;
    f16* PtW = &Pt[w][0];
    const unsigned pta = (unsigned)(size_t)((lf16*)PtW + l * 4);
    const int pbl = ((l15 >> 2) & 1) * 256 + (l15 >> 3) * 64 + (l15 & 3) * 16 + lq * 4;

    f32x4 acc_o[4][8];
#pragma unroll
    for (int rg = 0; rg < 4; ++rg)
#pragma unroll
        for (int i = 0; i < 8; ++i) acc_o[rg][i] = (f32x4){0.f, 0.f, 0.f, 0.f};
    float m_rg[4] = {-1e30f, -1e30f, -1e30f, -1e30f};
    float l_r[4][4];
#pragma unroll
    for (int rg = 0; rg < 4; ++rg)
#pragma unroll
        for (int r = 0; r < 4; ++r) l_r[rg][r] = 0.f;

    auto issue_tile = [&](int buf, int tile) {
        const size_t koff = (size_t)tile * 64 * GHD;
        const int KO = buf << 13;
#pragma unroll
        for (int i = 0; i < 4; ++i)
            __builtin_amdgcn_global_load_lds((gvoid*)(ksrc[i] + koff),
                                             (lvoid*)(kdst[i] + KO), 16, 0, 0);
#pragma unroll
        for (int i = 0; i < 4; ++i)
            __builtin_amdgcn_global_load_lds((gvoid*)(vsrc[i] + koff),
                                             (lvoid*)(vdst[i] + KO), 16, 0, 0);
    };

    auto compute_tile = [&](const f16* KsB, unsigned vtaB) {
        // ---- QK^T: S[64][64] per wave; each K-frag feeds 4 row-groups
        f32x4 sa[4][4];
        __builtin_amdgcn_s_setprio(1);
#pragma unroll
        for (int cb = 0; cb < 4; ++cb) {
#pragma unroll
            for (int rg = 0; rg < 4; ++rg)
                sa[rg][cb] = (f32x4){0.f, 0.f, 0.f, 0.f};
#pragma unroll
            for (int c = 0; c < 4; ++c) {
                const int rk = cb * 16 + l15;
                const f16x8 bk = *(const f16x8*)&KsB[rk * 128 + (((c * 4 + lq) ^ (rk & 7)) << 3)];
#pragma unroll
                for (int rg = 0; rg < 4; ++rg)
                    sa[rg][cb] = __builtin_amdgcn_mfma_f32_16x16x32_f16(aq[rg][c], bk, sa[rg][cb], 0, 0, 0);
            }
        }
        __builtin_amdgcn_s_setprio(0);

        // ---- softmax: group-max defer + exp2-direct; P stored transposed
#pragma unroll
        for (int rg = 0; rg < 4; ++rg) {
            float gm = sa[rg][0][0];
#pragma unroll
            for (int cb = 0; cb < 4; ++cb)
#pragma unroll
                for (int reg = 0; reg < 4; ++reg)
                    gm = fmaxf(gm, sa[rg][cb][reg]);
            gm = fmaxf(gm, __shfl_xor(gm, 1));
            gm = fmaxf(gm, __shfl_xor(gm, 2));
            gm = fmaxf(gm, __shfl_xor(gm, 4));
            gm = fmaxf(gm, __shfl_xor(gm, 8));
            if (gm > m_rg[rg] + 11.5f) {
                const float alpha = __builtin_amdgcn_exp2f(m_rg[rg] - gm);
                m_rg[rg] = gm;
#pragma unroll
                for (int reg = 0; reg < 4; ++reg) l_r[rg][reg] *= alpha;
#pragma unroll
                for (int db = 0; db < 8; ++db) acc_o[rg][db] *= alpha;
            }
#pragma unroll
            for (int cb = 0; cb < 4; ++cb) {
                f16x4 w4;
#pragma unroll
                for (int reg = 0; reg < 4; ++reg) {
                    const float p = __builtin_amdgcn_exp2f(sa[rg][cb][reg] - m_rg[rg]);
                    l_r[rg][reg] += p;
                    w4[reg] = (f16)p;
                }
                *(f16x4*)&PtW[rg * 1024 + (cb >> 1) * 512 + (cb & 1) * 128 + pbl] = w4;
            }
        }

        // ---- PV: per-db pipelined, counted lgkmcnt
        asm volatile("" ::: "memory");   // pin P-writes before the tr16 reads
        f16x8 pa[4][2];
#pragma unroll
        for (int rg = 0; rg < 4; ++rg) {
            f16x4 p0, p1, p2, p3;
            switch (rg) {
            case 0: p0 = tr16<0>(pta);    p1 = tr16<512>(pta);
                    p2 = tr16<1024>(pta); p3 = tr16<1536>(pta); break;
            case 1: p0 = tr16<2048>(pta); p1 = tr16<2560>(pta);
                    p2 = tr16<3072>(pta); p3 = tr16<3584>(pta); break;
            case 2: p0 = tr16<4096>(pta); p1 = tr16<4608>(pta);
                    p2 = tr16<5120>(pta); p3 = tr16<5632>(pta); break;
            default:p0 = tr16<6144>(pta); p1 = tr16<6656>(pta);
                    p2 = tr16<7168>(pta); p3 = tr16<7680>(pta); break;
            }
            pa[rg][0] = SHUF8(p0, p1);
            pa[rg][1] = SHUF8(p2, p3);
        }

        f16x8 v0k0, v0k1;
        {   // db = 0 V-frags
            f16x4 a0 = tr16<0>(vtaB),    b0 = tr16<512>(vtaB);
            f16x4 a1 = tr16<1024>(vtaB), b1 = tr16<1536>(vtaB);
            WAIT_LGKM(4);                // 32 P tr16 done (in-order DS); db0 V in flight
            v0k0 = SHUF8(a0, b0); v0k1 = SHUF8(a1, b1);
        }
#pragma unroll
        for (int db = 0; db < 8; ++db) {
            f16x8 n0, n1;
            if (db < 7) {
                f16x4 a0, b0, a1, b1;
                switch (db) {
                case 0: a0=tr16<2048>(vtaB);  b0=tr16<2560>(vtaB);  a1=tr16<3072>(vtaB);  b1=tr16<3584>(vtaB);  break;
                case 1: a0=tr16<4096>(vtaB);  b0=tr16<4608>(vtaB);  a1=tr16<5120>(vtaB);  b1=tr16<5632>(vtaB);  break;
                case 2: a0=tr16<6144>(vtaB);  b0=tr16<6656>(vtaB);  a1=tr16<7168>(vtaB);  b1=tr16<7680>(vtaB);  break;
                case 3: a0=tr16<8192>(vtaB);  b0=tr16<8704>(vtaB);  a1=tr16<9216>(vtaB);  b1=tr16<9728>(vtaB);  break;
                case 4: a0=tr16<10240>(vtaB); b0=tr16<10752>(vtaB); a1=tr16<11264>(vtaB); b1=tr16<11776>(vtaB); break;
                case 5: a0=tr16<12288>(vtaB); b0=tr16<12800>(vtaB); a1=tr16<13312>(vtaB); b1=tr16<13824>(vtaB); break;
                default:a0=tr16<14336>(vtaB); b0=tr16<14848>(vtaB); a1=tr16<15360>(vtaB); b1=tr16<15872>(vtaB); break;
                }
                WAIT_LGKM(4);            // V(db) done, V(db+1) in flight
                n0 = SHUF8(a0, b0); n1 = SHUF8(a1, b1);
            } else {
                WAIT_LGKM(0);
            }
            __builtin_amdgcn_s_setprio(1);
#pragma unroll
            for (int rg = 0; rg < 4; ++rg)
                acc_o[rg][db] = __builtin_amdgcn_mfma_f32_16x16x32_f16(pa[rg][0], v0k0, acc_o[rg][db], 0, 0, 0);
#pragma unroll
            for (int rg = 0; rg < 4; ++rg)
                acc_o[rg][db] = __builtin_amdgcn_mfma_f32_16x16x32_f16(pa[rg][1], v0k1, acc_o[rg][db], 0, 0, 0);
            __builtin_amdgcn_s_setprio(0);
            if (db < 7) { v0k0 = n0; v0k1 = n1; }
        }
    };

    // ---- pipelined main loop: 32 KV tiles, unrolled by 2 (static buffers)
    issue_tile(0, 0);
#pragma unroll 1
    for (int t2 = 0; t2 < 16; ++t2) {
        const int kt0 = t2 << 1;
        issue_tile(1, kt0 + 1);
        WAIT_VM8();
        BAR();
        compute_tile(&KsA[0][0], vta0);
        BAR();
        if (t2 < 15) {
            issue_tile(0, kt0 + 2);
            WAIT_VM8();
        } else {
            WAIT_VM0();
        }
        BAR();
        compute_tile(&KsA[1][0], vta1);
        BAR();
    }

    // ---- epilogue: reduce l across the 16-lane row group, normalize, store
    const size_t obase = (size_t)(b * SEQ + q0 + w * 64) * D_MODEL + h * HD;
#pragma unroll
    for (int rg = 0; rg < 4; ++rg) {
        float inv_l[4];
#pragma unroll
        for (int reg = 0; reg < 4; ++reg) {
            float s = l_r[rg][reg];
            s += __shfl_xor(s, 1);
            s += __shfl_xor(s, 2);
            s += __shfl_xor(s, 4);
            s += __shfl_xor(s, 8);
            inv_l[reg] = 1.f / s;
        }
#pragma unroll
        for (int db = 0; db < 8; ++db) {
#pragma unroll
            for (int reg = 0; reg < 4; ++reg) {
                const size_t off = obase + (size_t)(rg * 16 + lq * 4 + reg) * D_MODEL + db * 16 + l15;
                const float v = acc_o[rg][db][reg] * inv_l[reg];
                const f16 hh = (f16)v;
                AOh[off] = hh;
                AOl[off] = (f16)(v - (float)hh);
            }
        }
    }
}

extern "C" void kernel_launch(void* const* d_in, const int* in_sizes, int n_in,
                              void* d_out, int out_size, void* d_ws, size_t ws_size,
                              hipStream_t stream)
{
    const float* x  = (const float*)d_in[0];
    const float* Wq = (const float*)d_in[1];
    const float* bq = (const float*)d_in[2];
    const float* Wk = (const float*)d_in[3];
    const float* bk = (const float*)d_in[4];
    const float* Wv = (const float*)d_in[5];
    const float* bv = (const float*)d_in[6];
    const float* Wo = (const float*)d_in[7];
    const float* bo = (const float*)d_in[8];
    float* out = (float*)d_out;

    // workspace (f16 units), total 41,943,040 f16 = 83.9 MB.
    // AOh/AOl alias xh/xl (x dead after Q/KV GEMMs); Wo^T reuses Wq^T slot.
    f16* base  = (f16*)d_ws;
    f16* xh    = base;                 // 8388608
    f16* xl    = base + 8388608;       // 8388608
    f16* WkvT  = base + 16777216;      // 2097152 (K rows 0..511, V rows 512..1023)
    f16* WqoT  = base + 20971520;      // 4194304 (Wq, later Wo)
    f16* Qp    = base + 29360128;      // 8388608
    f16* Kp    = base + 37748736;      // 2097152
    f16* Vp    = base + 39845888;      // 2097152 -> end 41943040
    f16* AOh   = xh;
    f16* AOl   = xl;

    const dim3 blk(256);
    // 1/sqrt(128) * log2(e): scores arrive in log2 units for exp2-direct softmax
    const float qscale = 0.08838834764831845f * 1.4426950408889634f;

    split_f32<<<dim3(M_TOT * D_MODEL / 8 / 256), blk, 0, stream>>>(x, xh, xl);
    transpose_cast<<<dim3(64, 64), blk, 0, stream>>>(Wq, WqoT, 2048, 2048, 0);
    transpose_cast<<<dim3(16, 64), blk, 0, stream>>>(Wk, WkvT, 2048, 512, 0);
    transpose_cast<<<dim3(16, 64), blk, 0, stream>>>(Wv, WkvT, 2048, 512, 512);

    gemm_split<128, false><<<dim3(16, 32), blk, 0, stream>>>(
        xh, xl, WqoT, bq, bq, Qp, Qp, 2048, 2048, 2048, 2048, qscale);
    gemm_split<64, false><<<dim3(16, 32), blk, 0, stream>>>(
        xh, xl, WkvT, bk, bv, Kp, Vp, 512, 512, 512, 2048, 1.0f);

    // Wo^T into the (now dead) Wq^T slot, before attention overwrites xh/xl
    transpose_cast<<<dim3(64, 64), blk, 0, stream>>>(Wo, WqoT, 2048, 2048, 0);

    flash_attn_mfma<<<dim3(SEQ / 256, NQH, B_SZ), blk, 0, stream>>>(Qp, Kp, Vp, AOh, AOl);

    gemm_split<128, true><<<dim3(16, 32), blk, 0, stream>>>(
        AOh, AOl, WqoT, bo, bo, out, out, 2048, 2048, 2048, 2048, 1.0f);
}

// Round 11
// 340.796 us; speedup vs baseline: 1.1035x; 1.1035x over previous
//
#include <hip/hip_runtime.h>

#define D_MODEL 2048
#define GHD 512        // NUM_KV_GROUPS * HEAD_DIM
#define HD 128
#define NQH 16
#define B_SZ 2
#define SEQ 2048
#define M_TOT (B_SZ * SEQ)   // 4096

typedef _Float16 f16;
typedef __fp16 h16x2 __attribute__((ext_vector_type(2)));   // cvt_pkrtz native type
typedef _Float16 f16x4 __attribute__((ext_vector_type(4)));
typedef _Float16 f16x8 __attribute__((ext_vector_type(8)));
typedef float f32x4 __attribute__((ext_vector_type(4)));

typedef const __attribute__((address_space(1))) void gvoid;
typedef __attribute__((address_space(3))) void lvoid;
typedef __attribute__((address_space(3))) f16 lf16;

// raw barrier (no vmcnt(0) drain) with compiler fences
#define BAR() do { asm volatile("" ::: "memory"); \
                   __builtin_amdgcn_s_barrier();  \
                   asm volatile("" ::: "memory"); } while (0)
#define WAIT_VM8() asm volatile("s_waitcnt vmcnt(8)" ::: "memory")
#define WAIT_VM0() asm volatile("s_waitcnt vmcnt(0)" ::: "memory")
#define WAIT_LGKM(N) do { asm volatile("s_waitcnt lgkmcnt(" #N ")" ::: "memory"); \
                          __builtin_amdgcn_sched_barrier(0); } while (0)

// hardware transpose read: with per-lane addr = base + l*8B, lane l elem j
// reads f16 at base_f16[OFF/2 + (l>>4)*64 + j*16 + (l&15)]
template<int OFF>
__device__ __forceinline__ f16x4 tr16(unsigned a) {
    f16x4 d;
    asm volatile("ds_read_b64_tr_b16 %0, %1 offset:%2"
                 : "=v"(d) : "v"(a), "i"(OFF));
    return d;
}

// ---------------------------------------------------------------------------
// x (fp32) -> hi/lo f16 split, elementwise
// ---------------------------------------------------------------------------
__global__ __launch_bounds__(256) void split_f32(
    const float* __restrict__ X, f16* __restrict__ Xh, f16* __restrict__ Xl)
{
    const size_t i = ((size_t)blockIdx.x * 256 + threadIdx.x) * 8;
    const float4 v0 = *(const float4*)(X + i);
    const float4 v1 = *(const float4*)(X + i + 4);
    const float a[8] = {v0.x, v0.y, v0.z, v0.w, v1.x, v1.y, v1.z, v1.w};
    f16x8 h, lo;
#pragma unroll
    for (int e = 0; e < 8; ++e) {
        h[e] = (f16)a[e];
        lo[e] = (f16)(a[e] - (float)h[e]);
    }
    *(f16x8*)(Xh + i) = h;
    *(f16x8*)(Xl + i) = lo;
}

// ---------------------------------------------------------------------------
// Transpose + f16 cast: W[K][N] fp32 -> Th[(row_off+n)][K] f16
// ---------------------------------------------------------------------------
__global__ __launch_bounds__(256) void transpose_cast(
    const float* __restrict__ W, f16* __restrict__ Th,
    int K, int N, int row_off)
{
    __shared__ float Ls[32][33];
    const int t = threadIdx.x;
    const int n0 = blockIdx.x << 5, k0 = blockIdx.y << 5;
    {
        const int kr = t >> 3, nq = (t & 7) << 2;
        const float4 v = *(const float4*)&W[(size_t)(k0 + kr) * N + n0 + nq];
        Ls[kr][nq + 0] = v.x; Ls[kr][nq + 1] = v.y;
        Ls[kr][nq + 2] = v.z; Ls[kr][nq + 3] = v.w;
    }
    __syncthreads();
    const int nr = t >> 3, kq = (t & 7) << 2;
    f16x4 hv;
#pragma unroll
    for (int e = 0; e < 4; ++e) hv[e] = (f16)Ls[kq + e][nr];
    *(f16x4*)&Th[(size_t)(row_off + n0 + nr) * K + k0 + kq] = hv;
}

// ---------------------------------------------------------------------------
// 2-term split-precision MFMA GEMM: C = (Ah+Al) @ Bh^T + bias
// BM=128, BK=32, 256 threads (4 waves). XCD-aware block swizzle (T1).
// ---------------------------------------------------------------------------
template<int BN, bool OUT32>
__global__ __launch_bounds__(256) void gemm_split(
    const f16* __restrict__ Agh, const f16* __restrict__ Agl,
    const f16* __restrict__ BTh,
    const float* __restrict__ bias0, const float* __restrict__ bias1,
    void* __restrict__ C0v, void* __restrict__ C1v,
    int Nsplit, int ld0, int ld1, int K, float outscale)
{
    constexpr int WN = BN / 64;
    constexpr int WM = 4 / WN;
    constexpr int WI = 128 / (WM * 16);
    constexpr int LDK = 40;
    constexpr int NB = (BN * 4) / 256;

    __shared__ f16 Ah[128 * LDK], Al[128 * LDK];
    __shared__ f16 Bh[BN * LDK];

    const int tid = threadIdx.x;
    const int l = tid & 63, w = tid >> 6;
    const int l15 = l & 15, lq = l >> 4;
    const int wr = w / WN, wc = w % WN;

    // XCD swizzle: contiguous chunk of tiles per XCD
    const int nwgx = gridDim.x;
    const int orig = blockIdx.y * nwgx + blockIdx.x;
    const int cpx = (nwgx * gridDim.y) >> 3;
    const int sw = (orig & 7) * cpx + (orig >> 3);
    const int m0 = (sw / nwgx) << 7;
    const int n0 = (sw % nwgx) * BN;

    f32x4 acc[WI][4];
#pragma unroll
    for (int i = 0; i < WI; ++i)
#pragma unroll
        for (int j = 0; j < 4; ++j) acc[i][j] = (f32x4){0.f, 0.f, 0.f, 0.f};

    const int ar  = tid >> 2;
    const int auk = (tid & 3) << 3;
    const f16* Ahp = Agh + (size_t)(m0 + ar) * K + auk;
    const f16* Alp = Agl + (size_t)(m0 + ar) * K + auk;
    const int bnr = tid >> 2, buk = (tid & 3) << 3;
    const f16* Bhp = BTh + (size_t)(n0 + bnr) * K + buk;

    f16x8 a0h = *(const f16x8*)(Ahp);
    f16x8 a1h = *(const f16x8*)(Ahp + (size_t)64 * K);
    f16x8 a0l = *(const f16x8*)(Alp);
    f16x8 a1l = *(const f16x8*)(Alp + (size_t)64 * K);
    f16x8 bhv[NB];
#pragma unroll
    for (int it = 0; it < NB; ++it)
        bhv[it] = *(const f16x8*)(Bhp + (size_t)(it * 64) * K);

    for (int k0 = 0; k0 < K; k0 += 32) {
        __syncthreads();
        *(f16x8*)&Ah[ar * LDK + auk] = a0h;
        *(f16x8*)&Ah[(ar + 64) * LDK + auk] = a1h;
        *(f16x8*)&Al[ar * LDK + auk] = a0l;
        *(f16x8*)&Al[(ar + 64) * LDK + auk] = a1l;
#pragma unroll
        for (int it = 0; it < NB; ++it)
            *(f16x8*)&Bh[(bnr + it * 64) * LDK + buk] = bhv[it];
        __syncthreads();

        // prefetch next k0 (flies under MFMA; last-iter over-read stays in ws)
        const int kn = k0 + 32;
        a0h = *(const f16x8*)(Ahp + kn);
        a1h = *(const f16x8*)(Ahp + (size_t)64 * K + kn);
        a0l = *(const f16x8*)(Alp + kn);
        a1l = *(const f16x8*)(Alp + (size_t)64 * K + kn);
#pragma unroll
        for (int it = 0; it < NB; ++it)
            bhv[it] = *(const f16x8*)(Bhp + (size_t)(it * 64) * K + kn);

        f16x8 afh[WI], afl[WI];
#pragma unroll
        for (int i = 0; i < WI; ++i) {
            const int row = wr * (WI * 16) + i * 16 + l15;
            afh[i] = *(const f16x8*)&Ah[row * LDK + lq * 8];
            afl[i] = *(const f16x8*)&Al[row * LDK + lq * 8];
        }
#pragma unroll
        for (int j = 0; j < 4; ++j) {
            const int bn = wc * 64 + j * 16 + l15;
            const f16x8 bfh = *(const f16x8*)&Bh[bn * LDK + lq * 8];
#pragma unroll
            for (int i = 0; i < WI; ++i)
                acc[i][j] = __builtin_amdgcn_mfma_f32_16x16x32_f16(afh[i], bfh, acc[i][j], 0, 0, 0);
#pragma unroll
            for (int i = 0; i < WI; ++i)
                acc[i][j] = __builtin_amdgcn_mfma_f32_16x16x32_f16(afl[i], bfh, acc[i][j], 0, 0, 0);
        }
    }

#pragma unroll
    for (int j = 0; j < 4; ++j) {
        const int ng = n0 + wc * 64 + j * 16 + l15;
        const bool first = ng < Nsplit;
        const float bvf = first ? bias0[ng] : bias1[ng - Nsplit];
        const int nc = first ? ng : ng - Nsplit;
        const int ldc = first ? ld0 : ld1;
#pragma unroll
        for (int i = 0; i < WI; ++i) {
            const int mg = m0 + wr * (WI * 16) + i * 16 + lq * 4;
#pragma unroll
            for (int r = 0; r < 4; ++r) {
                const float v = (acc[i][j][r] + bvf) * outscale;
                if (OUT32)
                    ((float*)(first ? C0v : C1v))[(size_t)(mg + r) * ldc + nc] = v;
                else
                    ((f16*)(first ? C0v : C1v))[(size_t)(mg + r) * ldc + nc] = (f16)v;
            }
        }
    }
}

#define SHUF8(x, y) __builtin_shufflevector(x, y, 0, 1, 2, 3, 4, 5, 6, 7)

// ---------------------------------------------------------------------------
// fp16-MFMA flash attention v6: 4 waves x 32 q-rows (QBLK=128, rg=2,
// 2 blocks/CU = 2 waves/SIMD). Swapped QK^T — mfma(A=K, B=Q) puts scores as
// S[k][q=l15], so each lane's 16 P values are exactly its PV A-fragment:
// P packed in-register via v_cvt_pkrtz (16 ops), ZERO P LDS traffic.
// V row order in the tr16 subtile store permuted to match the A-frag k
// ordering: kv = (kc<<5)|(jh<<4)|(vlq<<2)|kvlo. Per-q softmax max via
// xor16/xor32 shuffles + wave-uniform ballot defer; V tr16 for db0/db1
// issued before the softmax VALU (no P dependency) so PV lgkm waits are free.
// ---------------------------------------------------------------------------
__global__ __launch_bounds__(256, 2) void flash_attn_mfma(
    const f16* __restrict__ Q, const f16* __restrict__ Kp,
    const f16* __restrict__ Vp, f16* __restrict__ AOh, f16* __restrict__ AOl)
{
    __shared__ f16 KsA[2][64 * 128];   // 32 KB
    __shared__ f16 VtA[2][64 * 128];   // 32 KB (tr16 subtiled, permuted rows)

    const int tid = threadIdx.x;
    const int w = tid >> 6, l = tid & 63;
    const int l15 = l & 15, lq = l >> 4;
    const int b = blockIdx.z, h = blockIdx.y, g = h >> 2;
    const int q0 = blockIdx.x << 7;    // 128 q-rows per block

    const f16* Qb = Q + (size_t)(b * SEQ + q0) * D_MODEL + h * HD;
    const f16* Kb = Kp + (size_t)b * SEQ * GHD + g * HD;
    const f16* Vb = Vp + (size_t)b * SEQ * GHD + g * HD;

    // Q fragments: wave owns rows [w*32, w*32+32) as 2 groups of 16.
    // Used as the B operand of the swapped QK^T (B col = l15 = q).
    f16x8 aq[2][4];
#pragma unroll
    for (int rg = 0; rg < 2; ++rg) {
        const f16* qrow = Qb + (size_t)(w * 32 + rg * 16 + l15) * D_MODEL;
#pragma unroll
        for (int c = 0; c < 4; ++c)
            aq[rg][c] = *(const f16x8*)(qrow + c * 32 + lq * 8);
    }

    // staging addresses (per-lane-permuted global source, linear LDS dest)
    lf16* Ks3 = (lf16*)&KsA[0][0];
    lf16* Vt3 = (lf16*)&VtA[0][0];
    const f16* ksrc[4]; lf16* kdst[4];
    const f16* vsrc[4]; lf16* vdst[4];
#pragma unroll
    for (int i = 0; i < 4; ++i) {
        const int s = tid + (i << 8);
        {
            const int row = s >> 4, ul = s & 15;
            ksrc[i] = Kb + (size_t)row * GHD + ((ul ^ (row & 7)) << 3);
            kdst[i] = Ks3 + s * 8;
        }
        {
            // slot s_k = kc*32 + vlq*8 + jh*4 + kvlo ; phys kv = sigma(slot)
            // sigma: kv = 32*kc + 16*jh + 4*vlq + kvlo  (matches the in-reg
            // P packing: A-frag elem j=jh*4+kvlo <-> cb=2kc+jh, reg=kvlo)
            const int dbit = s & 1, kvlo = (s >> 1) & 3, vlq = (s >> 3) & 3;
            const int jh = (s >> 5) & 1, kc = (s >> 6) & 1, dsub = s >> 7;
            const int kv = (kc << 5) | (jh << 4) | (vlq << 2) | kvlo;
            vsrc[i] = Vb + (size_t)kv * GHD + ((dsub << 4) | (dbit << 3));
            vdst[i] = Vt3 + s * 8;
        }
    }
    const unsigned vta0 = (unsigned)(size_t)(Vt3 + l * 4);
    const unsigned vta1 = vta0 + 16384;

    f32x4 acc_o[2][8];
#pragma unroll
    for (int rg = 0; rg < 2; ++rg)
#pragma unroll
        for (int i = 0; i < 8; ++i) acc_o[rg][i] = (f32x4){0.f, 0.f, 0.f, 0.f};
    float m_q[2] = {-1e30f, -1e30f};   // per-lane running max for q = l15
    float l_q[2] = {0.f, 0.f};         // per-lane partial row sum for q = l15

    auto issue_tile = [&](int buf, int tile) {
        const size_t koff = (size_t)tile * 64 * GHD;
        const int KO = buf << 13;
#pragma unroll
        for (int i = 0; i < 4; ++i)
            __builtin_amdgcn_global_load_lds((gvoid*)(ksrc[i] + koff),
                                             (lvoid*)(kdst[i] + KO), 16, 0, 0);
#pragma unroll
        for (int i = 0; i < 4; ++i)
            __builtin_amdgcn_global_load_lds((gvoid*)(vsrc[i] + koff),
                                             (lvoid*)(vdst[i] + KO), 16, 0, 0);
    };

    auto compute_tile = [&](const f16* KsB, unsigned vtaB) {
        // ---- swapped QK^T: sa[rg][cb][reg] = S[k=cb*16+lq*4+reg][q=l15]
        f32x4 sa[2][4];
        __builtin_amdgcn_s_setprio(1);
#pragma unroll
        for (int cb = 0; cb < 4; ++cb) {
            sa[0][cb] = (f32x4){0.f, 0.f, 0.f, 0.f};
            sa[1][cb] = (f32x4){0.f, 0.f, 0.f, 0.f};
#pragma unroll
            for (int c = 0; c < 4; ++c) {
                const int rk = cb * 16 + l15;
                const f16x8 bk = *(const f16x8*)&KsB[rk * 128 + (((c * 4 + lq) ^ (rk & 7)) << 3)];
                sa[0][cb] = __builtin_amdgcn_mfma_f32_16x16x32_f16(bk, aq[0][c], sa[0][cb], 0, 0, 0);
                sa[1][cb] = __builtin_amdgcn_mfma_f32_16x16x32_f16(bk, aq[1][c], sa[1][cb], 0, 0, 0);
            }
        }
        __builtin_amdgcn_s_setprio(0);

        // ---- per-q tile max + deferred rescale (wave-uniform ballot branch)
#pragma unroll
        for (int rg = 0; rg < 2; ++rg) {
            float gm = sa[rg][0][0];
#pragma unroll
            for (int cb = 0; cb < 4; ++cb)
#pragma unroll
                for (int reg = 0; reg < 4; ++reg)
                    gm = fmaxf(gm, sa[rg][cb][reg]);
            gm = fmaxf(gm, __shfl_xor(gm, 16));
            gm = fmaxf(gm, __shfl_xor(gm, 32));      // gm = tile max for q=l15
            if (__ballot(gm > m_q[rg] + 11.5f)) {    // rare path
                const float mnew = fmaxf(m_q[rg], gm);
                const float alpha = __builtin_amdgcn_exp2f(m_q[rg] - mnew);
                m_q[rg] = mnew;
                l_q[rg] *= alpha;
                f32x4 av;
#pragma unroll
                for (int reg = 0; reg < 4; ++reg)
                    av[reg] = __shfl(alpha, lq * 4 + reg);   // alpha of q=lq*4+reg
#pragma unroll
                for (int db = 0; db < 8; ++db) acc_o[rg][db] *= av;
            }
        }

        // ---- issue V tr16 for db0 + db1 now (no P dependency) — they retire
        // under the exp/pack VALU below.
        f16x4 va0 = tr16<0>(vtaB),    vb0 = tr16<512>(vtaB);
        f16x4 va1 = tr16<1024>(vtaB), vb1 = tr16<1536>(vtaB);
        f16x4 ca0 = tr16<2048>(vtaB), cb0 = tr16<2560>(vtaB);
        f16x4 ca1 = tr16<3072>(vtaB), cb1 = tr16<3584>(vtaB);

        // ---- p = exp2(sa - m), per-lane row-sum, pack to PV A-frags in-reg
        f16x8 pa[2][2];
#pragma unroll
        for (int rg = 0; rg < 2; ++rg) {
            float ps = 0.f;
#pragma unroll
            for (int cb = 0; cb < 4; ++cb)
#pragma unroll
                for (int reg = 0; reg < 4; ++reg) {
                    const float p = __builtin_amdgcn_exp2f(sa[rg][cb][reg] - m_q[rg]);
                    sa[rg][cb][reg] = p;
                    ps += p;
                }
            l_q[rg] += ps;
#pragma unroll
            for (int kc = 0; kc < 2; ++kc) {
                union { h16x2 h2[4]; f16x8 h8; } u;
                u.h2[0] = __builtin_amdgcn_cvt_pkrtz(sa[rg][2 * kc][0], sa[rg][2 * kc][1]);
                u.h2[1] = __builtin_amdgcn_cvt_pkrtz(sa[rg][2 * kc][2], sa[rg][2 * kc][3]);
                u.h2[2] = __builtin_amdgcn_cvt_pkrtz(sa[rg][2 * kc + 1][0], sa[rg][2 * kc + 1][1]);
                u.h2[3] = __builtin_amdgcn_cvt_pkrtz(sa[rg][2 * kc + 1][2], sa[rg][2 * kc + 1][3]);
                pa[rg][kc] = u.h8;
            }
        }

        // ---- PV: per-db pipelined, counted lgkmcnt (SHUF strictly after wait)
        WAIT_LGKM(4);                       // db0 retired (db1 in flight)
        f16x8 v0 = SHUF8(va0, vb0), v1 = SHUF8(va1, vb1);
#pragma unroll
        for (int db = 0; db < 8; ++db) {
            f16x4 ma0, mb0, ma1, mb1;
            if (db < 6) {
                switch (db) {               // issue db+2: (db+2)*2048 + kc*1024 + half*512
                case 0: ma0=tr16<4096>(vtaB);  mb0=tr16<4608>(vtaB);  ma1=tr16<5120>(vtaB);  mb1=tr16<5632>(vtaB);  break;
                case 1: ma0=tr16<6144>(vtaB);  mb0=tr16<6656>(vtaB);  ma1=tr16<7168>(vtaB);  mb1=tr16<7680>(vtaB);  break;
                case 2: ma0=tr16<8192>(vtaB);  mb0=tr16<8704>(vtaB);  ma1=tr16<9216>(vtaB);  mb1=tr16<9728>(vtaB);  break;
                case 3: ma0=tr16<10240>(vtaB); mb0=tr16<10752>(vtaB); ma1=tr16<11264>(vtaB); mb1=tr16<11776>(vtaB); break;
                case 4: ma0=tr16<12288>(vtaB); mb0=tr16<12800>(vtaB); ma1=tr16<13312>(vtaB); mb1=tr16<13824>(vtaB); break;
                default:ma0=tr16<14336>(vtaB); mb0=tr16<14848>(vtaB); ma1=tr16<15360>(vtaB); mb1=tr16<15872>(vtaB); break;
                }
                WAIT_LGKM(4);               // db+1 retired (its 4 are oldest of 8)
            } else if (db == 6) {
                WAIT_LGKM(0);               // db7 retired
            }
            f16x8 n0, n1;
            if (db < 7) { n0 = SHUF8(ca0, cb0); n1 = SHUF8(ca1, cb1); }
            __builtin_amdgcn_s_setprio(1);
            acc_o[0][db] = __builtin_amdgcn_mfma_f32_16x16x32_f16(pa[0][0], v0, acc_o[0][db], 0, 0, 0);
            acc_o[1][db] = __builtin_amdgcn_mfma_f32_16x16x32_f16(pa[1][0], v0, acc_o[1][db], 0, 0, 0);
            acc_o[0][db] = __builtin_amdgcn_mfma_f32_16x16x32_f16(pa[0][1], v1, acc_o[0][db], 0, 0, 0);
            acc_o[1][db] = __builtin_amdgcn_mfma_f32_16x16x32_f16(pa[1][1], v1, acc_o[1][db], 0, 0, 0);
            __builtin_amdgcn_s_setprio(0);
            if (db < 7) {
                v0 = n0; v1 = n1;
                ca0 = ma0; cb0 = mb0; ca1 = ma1; cb1 = mb1;
            }
        }
    };

    // ---- pipelined main loop: 32 KV tiles, unrolled by 2 (static buffers)
    issue_tile(0, 0);
#pragma unroll 1
    for (int t2 = 0; t2 < 16; ++t2) {
        const int kt0 = t2 << 1;
        issue_tile(1, kt0 + 1);
        WAIT_VM8();
        BAR();
        compute_tile(&KsA[0][0], vta0);
        BAR();
        if (t2 < 15) {
            issue_tile(0, kt0 + 2);
            WAIT_VM8();
        } else {
            WAIT_VM0();
        }
        BAR();
        compute_tile(&KsA[1][0], vta1);
        BAR();
    }

    // ---- epilogue: reduce l over k-complement lanes (xor16/32), broadcast
    // per-q inverse to the acc rows, normalize, store hi/lo f16
    const size_t obase = (size_t)(b * SEQ + q0 + w * 32) * D_MODEL + h * HD;
#pragma unroll
    for (int rg = 0; rg < 2; ++rg) {
        float lr = l_q[rg];
        lr += __shfl_xor(lr, 16);
        lr += __shfl_xor(lr, 32);          // lane now holds l[q=l15]
        float inv_l[4];
#pragma unroll
        for (int reg = 0; reg < 4; ++reg)
            inv_l[reg] = 1.f / __shfl(lr, lq * 4 + reg);
#pragma unroll
        for (int db = 0; db < 8; ++db) {
#pragma unroll
            for (int reg = 0; reg < 4; ++reg) {
                const size_t off = obase + (size_t)(rg * 16 + lq * 4 + reg) * D_MODEL + db * 16 + l15;
                const float v = acc_o[rg][db][reg] * inv_l[reg];
                const f16 hh = (f16)v;
                AOh[off] = hh;
                AOl[off] = (f16)(v - (float)hh);
            }
        }
    }
}

extern "C" void kernel_launch(void* const* d_in, const int* in_sizes, int n_in,
                              void* d_out, int out_size, void* d_ws, size_t ws_size,
                              hipStream_t stream)
{
    const float* x  = (const float*)d_in[0];
    const float* Wq = (const float*)d_in[1];
    const float* bq = (const float*)d_in[2];
    const float* Wk = (const float*)d_in[3];
    const float* bk = (const float*)d_in[4];
    const float* Wv = (const float*)d_in[5];
    const float* bv = (const float*)d_in[6];
    const float* Wo = (const float*)d_in[7];
    const float* bo = (const float*)d_in[8];
    float* out = (float*)d_out;

    // workspace (f16 units), total 41,943,040 f16 = 83.9 MB.
    // AOh/AOl alias xh/xl (x dead after Q/KV GEMMs); Wo^T reuses Wq^T slot.
    f16* base  = (f16*)d_ws;
    f16* xh    = base;                 // 8388608
    f16* xl    = base + 8388608;       // 8388608
    f16* WkvT  = base + 16777216;      // 2097152 (K rows 0..511, V rows 512..1023)
    f16* WqoT  = base + 20971520;      // 4194304 (Wq, later Wo)
    f16* Qp    = base + 29360128;      // 8388608
    f16* Kp    = base + 37748736;      // 2097152
    f16* Vp    = base + 39845888;      // 2097152 -> end 41943040
    f16* AOh   = xh;
    f16* AOl   = xl;

    const dim3 blk(256);
    // 1/sqrt(128) * log2(e): scores arrive in log2 units for exp2-direct softmax
    const float qscale = 0.08838834764831845f * 1.4426950408889634f;

    split_f32<<<dim3(M_TOT * D_MODEL / 8 / 256), blk, 0, stream>>>(x, xh, xl);
    transpose_cast<<<dim3(64, 64), blk, 0, stream>>>(Wq, WqoT, 2048, 2048, 0);
    transpose_cast<<<dim3(16, 64), blk, 0, stream>>>(Wk, WkvT, 2048, 512, 0);
    transpose_cast<<<dim3(16, 64), blk, 0, stream>>>(Wv, WkvT, 2048, 512, 512);

    gemm_split<128, false><<<dim3(16, 32), blk, 0, stream>>>(
        xh, xl, WqoT, bq, bq, Qp, Qp, 2048, 2048, 2048, 2048, qscale);
    gemm_split<64, false><<<dim3(16, 32), blk, 0, stream>>>(
        xh, xl, WkvT, bk, bv, Kp, Vp, 512, 512, 512, 2048, 1.0f);

    // Wo^T into the (now dead) Wq^T slot, before attention overwrites xh/xl
    transpose_cast<<<dim3(64, 64), blk, 0, stream>>>(Wo, WqoT, 2048, 2048, 0);

    flash_attn_mfma<<<dim3(SEQ / 128, NQH, B_SZ), blk, 0, stream>>>(Qp, Kp, Vp, AOh, AOl);

    gemm_split<128, true><<<dim3(16, 32), blk, 0, stream>>>(
        AOh, AOl, WqoT, bo, bo, out, out, 2048, 2048, 2048, 2048, 1.0f);
}

// Round 12
// 254.896 us; speedup vs baseline: 1.4754x; 1.3370x over previous
//
#include <hip/hip_runtime.h>

#define D_MODEL 2048
#define GHD 512        // NUM_KV_GROUPS * HEAD_DIM
#define HD 128
#define NQH 16
#define B_SZ 2
#define SEQ 2048
#define M_TOT (B_SZ * SEQ)   // 4096

typedef _Float16 f16;
typedef __fp16 h16x2 __attribute__((ext_vector_type(2)));   // cvt_pkrtz native type
typedef _Float16 f16x4 __attribute__((ext_vector_type(4)));
typedef _Float16 f16x8 __attribute__((ext_vector_type(8)));
typedef float f32x4 __attribute__((ext_vector_type(4)));

typedef const __attribute__((address_space(1))) void gvoid;
typedef __attribute__((address_space(3))) void lvoid;
typedef __attribute__((address_space(3))) f16 lf16;

// raw barrier (no vmcnt(0) drain) with compiler fences
#define BAR() do { asm volatile("" ::: "memory"); \
                   __builtin_amdgcn_s_barrier();  \
                   asm volatile("" ::: "memory"); } while (0)
#define WAIT_VM8() asm volatile("s_waitcnt vmcnt(8)" ::: "memory")
#define WAIT_VM0() asm volatile("s_waitcnt vmcnt(0)" ::: "memory")
#define WAIT_LGKM(N) do { asm volatile("s_waitcnt lgkmcnt(" #N ")" ::: "memory"); \
                          __builtin_amdgcn_sched_barrier(0); } while (0)

// hardware transpose read: with per-lane addr = base + l*8B, lane l elem j
// reads f16 at base_f16[OFF/2 + (l>>4)*64 + j*16 + (l&15)]
template<int OFF>
__device__ __forceinline__ f16x4 tr16(unsigned a) {
    f16x4 d;
    asm volatile("ds_read_b64_tr_b16 %0, %1 offset:%2"
                 : "=v"(d) : "v"(a), "i"(OFF));
    return d;
}

// ---------------------------------------------------------------------------
// x (fp32) -> f16 cast, elementwise (hi only — Q/KV GEMMs are 1-term now)
// ---------------------------------------------------------------------------
__global__ __launch_bounds__(256) void cast_f16(
    const float* __restrict__ X, f16* __restrict__ Xh)
{
    const size_t i = ((size_t)blockIdx.x * 256 + threadIdx.x) * 8;
    const float4 v0 = *(const float4*)(X + i);
    const float4 v1 = *(const float4*)(X + i + 4);
    f16x8 h;
    h[0] = (f16)v0.x; h[1] = (f16)v0.y; h[2] = (f16)v0.z; h[3] = (f16)v0.w;
    h[4] = (f16)v1.x; h[5] = (f16)v1.y; h[6] = (f16)v1.z; h[7] = (f16)v1.w;
    *(f16x8*)(Xh + i) = h;
}

// ---------------------------------------------------------------------------
// Transpose + f16 cast: W[K][N] fp32 -> Th[(row_off+n)][K] f16
// ---------------------------------------------------------------------------
__global__ __launch_bounds__(256) void transpose_cast(
    const float* __restrict__ W, f16* __restrict__ Th,
    int K, int N, int row_off)
{
    __shared__ float Ls[32][33];
    const int t = threadIdx.x;
    const int n0 = blockIdx.x << 5, k0 = blockIdx.y << 5;
    {
        const int kr = t >> 3, nq = (t & 7) << 2;
        const float4 v = *(const float4*)&W[(size_t)(k0 + kr) * N + n0 + nq];
        Ls[kr][nq + 0] = v.x; Ls[kr][nq + 1] = v.y;
        Ls[kr][nq + 2] = v.z; Ls[kr][nq + 3] = v.w;
    }
    __syncthreads();
    const int nr = t >> 3, kq = (t & 7) << 2;
    f16x4 hv;
#pragma unroll
    for (int e = 0; e < 4; ++e) hv[e] = (f16)Ls[kq + e][nr];
    *(f16x4*)&Th[(size_t)(row_off + n0 + nr) * K + k0 + kq] = hv;
}

// ---------------------------------------------------------------------------
// MFMA GEMM, BK=64 (half the barrier phases of the BK=32 version — the
// measured ~67 us/dispatch floor was barrier-drain-proportional).
// TWOTERM: C = (Ah+Al) @ Bh^T + bias (used for O-proj); else pure f16 1-term.
// BM=128, 256 threads (4 waves). LDK=72 pad -> all LDS ops 8-group-uniform
// on banks: frag group = (l15+lq+4c) mod 8, write group = ((t>>3)+(t&7)) mod 8.
// XCD-aware block swizzle (T1). Prefetch over-reads on the last k-iteration
// stay inside d_ws (verified per workspace layout).
// ---------------------------------------------------------------------------
template<int BN, bool OUT32, bool TWOTERM>
__global__ __launch_bounds__(256) void gemm_bk64(
    const f16* __restrict__ Agh, const f16* __restrict__ Agl,
    const f16* __restrict__ BTh,
    const float* __restrict__ bias0, const float* __restrict__ bias1,
    void* __restrict__ C0v, void* __restrict__ C1v,
    int Nsplit, int ld0, int ld1, int K, float outscale)
{
    constexpr int WN = BN / 64;           // waves along n
    constexpr int WM = 4 / WN;            // waves along m
    constexpr int WI = 128 / (WM * 16);   // m-frags per wave
    constexpr int LDK = 72;               // padded row (f16)
    constexpr int NBP = BN / 32;          // B staging passes (4 or 2)

    __shared__ f16 Ah[128 * LDK];
    __shared__ f16 Al[TWOTERM ? 128 * LDK : 8];
    __shared__ f16 Bh[BN * LDK];

    const int tid = threadIdx.x;
    const int l = tid & 63, w = tid >> 6;
    const int l15 = l & 15, lq = l >> 4;
    const int wr = w / WN, wc = w % WN;

    // XCD swizzle: contiguous chunk of tiles per XCD (nwg = 512, div by 8)
    const int nwgx = gridDim.x;
    const int orig = blockIdx.y * nwgx + blockIdx.x;
    const int cpx = (nwgx * gridDim.y) >> 3;
    const int sw = (orig & 7) * cpx + (orig >> 3);
    const int m0 = (sw / nwgx) << 7;
    const int n0 = (sw % nwgx) * BN;

    f32x4 acc[WI][4];
#pragma unroll
    for (int i = 0; i < WI; ++i)
#pragma unroll
        for (int j = 0; j < 4; ++j) acc[i][j] = (f32x4){0.f, 0.f, 0.f, 0.f};

    // staging mapping: 16B chunk per thread per pass; pass advances row by 32
    const int srow = tid >> 3;            // 0..31
    const int skc  = (tid & 7) << 3;      // 0,8,..,56 (f16)
    const f16* Ap  = Agh + (size_t)(m0 + srow) * K + skc;
    const f16* Alp = TWOTERM ? (Agl + (size_t)(m0 + srow) * K + skc) : nullptr;
    const f16* Bp  = BTh + (size_t)(n0 + srow) * K + skc;

    f16x8 av[4], alv[TWOTERM ? 4 : 1], bv[NBP];
#pragma unroll
    for (int p = 0; p < 4; ++p)
        av[p] = *(const f16x8*)(Ap + (size_t)(p * 32) * K);
    if constexpr (TWOTERM) {
#pragma unroll
        for (int p = 0; p < 4; ++p)
            alv[p] = *(const f16x8*)(Alp + (size_t)(p * 32) * K);
    }
#pragma unroll
    for (int p = 0; p < NBP; ++p)
        bv[p] = *(const f16x8*)(Bp + (size_t)(p * 32) * K);

    for (int k0 = 0; k0 < K; k0 += 64) {
        __syncthreads();   // previous iteration's fragment reads done
#pragma unroll
        for (int p = 0; p < 4; ++p)
            *(f16x8*)&Ah[(srow + p * 32) * LDK + skc] = av[p];
        if constexpr (TWOTERM) {
#pragma unroll
            for (int p = 0; p < 4; ++p)
                *(f16x8*)&Al[(srow + p * 32) * LDK + skc] = alv[p];
        }
#pragma unroll
        for (int p = 0; p < NBP; ++p)
            *(f16x8*)&Bh[(srow + p * 32) * LDK + skc] = bv[p];
        __syncthreads();

        // prefetch next k0 (flies under MFMA; last-iter over-read stays in ws)
        const int kn = k0 + 64;
#pragma unroll
        for (int p = 0; p < 4; ++p)
            av[p] = *(const f16x8*)(Ap + (size_t)(p * 32) * K + kn);
        if constexpr (TWOTERM) {
#pragma unroll
            for (int p = 0; p < 4; ++p)
                alv[p] = *(const f16x8*)(Alp + (size_t)(p * 32) * K + kn);
        }
#pragma unroll
        for (int p = 0; p < NBP; ++p)
            bv[p] = *(const f16x8*)(Bp + (size_t)(p * 32) * K + kn);

#pragma unroll
        for (int c = 0; c < 2; ++c) {
            f16x8 afh[WI], afl[WI];
#pragma unroll
            for (int i = 0; i < WI; ++i) {
                const int row = wr * (WI * 16) + i * 16 + l15;
                afh[i] = *(const f16x8*)&Ah[row * LDK + c * 32 + lq * 8];
                if constexpr (TWOTERM)
                    afl[i] = *(const f16x8*)&Al[row * LDK + c * 32 + lq * 8];
            }
#pragma unroll
            for (int j = 0; j < 4; ++j) {
                const int bn = wc * 64 + j * 16 + l15;
                const f16x8 bfh = *(const f16x8*)&Bh[bn * LDK + c * 32 + lq * 8];
#pragma unroll
                for (int i = 0; i < WI; ++i)
                    acc[i][j] = __builtin_amdgcn_mfma_f32_16x16x32_f16(afh[i], bfh, acc[i][j], 0, 0, 0);
                if constexpr (TWOTERM) {
#pragma unroll
                    for (int i = 0; i < WI; ++i)
                        acc[i][j] = __builtin_amdgcn_mfma_f32_16x16x32_f16(afl[i], bfh, acc[i][j], 0, 0, 0);
                }
            }
        }
    }

#pragma unroll
    for (int j = 0; j < 4; ++j) {
        const int ng = n0 + wc * 64 + j * 16 + l15;
        const bool first = ng < Nsplit;
        const float bvf = first ? bias0[ng] : bias1[ng - Nsplit];
        const int nc = first ? ng : ng - Nsplit;
        const int ldc = first ? ld0 : ld1;
#pragma unroll
        for (int i = 0; i < WI; ++i) {
            const int mg = m0 + wr * (WI * 16) + i * 16 + lq * 4;
#pragma unroll
            for (int r = 0; r < 4; ++r) {
                const float v = (acc[i][j][r] + bvf) * outscale;
                if (OUT32)
                    ((float*)(first ? C0v : C1v))[(size_t)(mg + r) * ldc + nc] = v;
                else
                    ((f16*)(first ? C0v : C1v))[(size_t)(mg + r) * ldc + nc] = (f16)v;
            }
        }
    }
}

#define SHUF8(x, y) __builtin_shufflevector(x, y, 0, 1, 2, 3, 4, 5, 6, 7)

// ---------------------------------------------------------------------------
// fp16-MFMA flash attention v6 (unchanged from round 11 — passed):
// 4 waves x 32 q-rows, swapped QK^T (P in-register via cvt_pkrtz, zero P LDS),
// permuted V tr16 subtiles, per-q ballot-deferred softmax, double-buffered
// K/V via global_load_lds + counted vmcnt + raw barriers, hi/lo f16 output.
// ---------------------------------------------------------------------------
__global__ __launch_bounds__(256, 2) void flash_attn_mfma(
    const f16* __restrict__ Q, const f16* __restrict__ Kp,
    const f16* __restrict__ Vp, f16* __restrict__ AOh, f16* __restrict__ AOl)
{
    __shared__ f16 KsA[2][64 * 128];   // 32 KB
    __shared__ f16 VtA[2][64 * 128];   // 32 KB (tr16 subtiled, permuted rows)

    const int tid = threadIdx.x;
    const int w = tid >> 6, l = tid & 63;
    const int l15 = l & 15, lq = l >> 4;
    const int b = blockIdx.z, h = blockIdx.y, g = h >> 2;
    const int q0 = blockIdx.x << 7;    // 128 q-rows per block

    const f16* Qb = Q + (size_t)(b * SEQ + q0) * D_MODEL + h * HD;
    const f16* Kb = Kp + (size_t)b * SEQ * GHD + g * HD;
    const f16* Vb = Vp + (size_t)b * SEQ * GHD + g * HD;

    f16x8 aq[2][4];
#pragma unroll
    for (int rg = 0; rg < 2; ++rg) {
        const f16* qrow = Qb + (size_t)(w * 32 + rg * 16 + l15) * D_MODEL;
#pragma unroll
        for (int c = 0; c < 4; ++c)
            aq[rg][c] = *(const f16x8*)(qrow + c * 32 + lq * 8);
    }

    lf16* Ks3 = (lf16*)&KsA[0][0];
    lf16* Vt3 = (lf16*)&VtA[0][0];
    const f16* ksrc[4]; lf16* kdst[4];
    const f16* vsrc[4]; lf16* vdst[4];
#pragma unroll
    for (int i = 0; i < 4; ++i) {
        const int s = tid + (i << 8);
        {
            const int row = s >> 4, ul = s & 15;
            ksrc[i] = Kb + (size_t)row * GHD + ((ul ^ (row & 7)) << 3);
            kdst[i] = Ks3 + s * 8;
        }
        {
            const int dbit = s & 1, kvlo = (s >> 1) & 3, vlq = (s >> 3) & 3;
            const int jh = (s >> 5) & 1, kc = (s >> 6) & 1, dsub = s >> 7;
            const int kv = (kc << 5) | (jh << 4) | (vlq << 2) | kvlo;
            vsrc[i] = Vb + (size_t)kv * GHD + ((dsub << 4) | (dbit << 3));
            vdst[i] = Vt3 + s * 8;
        }
    }
    const unsigned vta0 = (unsigned)(size_t)(Vt3 + l * 4);
    const unsigned vta1 = vta0 + 16384;

    f32x4 acc_o[2][8];
#pragma unroll
    for (int rg = 0; rg < 2; ++rg)
#pragma unroll
        for (int i = 0; i < 8; ++i) acc_o[rg][i] = (f32x4){0.f, 0.f, 0.f, 0.f};
    float m_q[2] = {-1e30f, -1e30f};
    float l_q[2] = {0.f, 0.f};

    auto issue_tile = [&](int buf, int tile) {
        const size_t koff = (size_t)tile * 64 * GHD;
        const int KO = buf << 13;
#pragma unroll
        for (int i = 0; i < 4; ++i)
            __builtin_amdgcn_global_load_lds((gvoid*)(ksrc[i] + koff),
                                             (lvoid*)(kdst[i] + KO), 16, 0, 0);
#pragma unroll
        for (int i = 0; i < 4; ++i)
            __builtin_amdgcn_global_load_lds((gvoid*)(vsrc[i] + koff),
                                             (lvoid*)(vdst[i] + KO), 16, 0, 0);
    };

    auto compute_tile = [&](const f16* KsB, unsigned vtaB) {
        f32x4 sa[2][4];
        __builtin_amdgcn_s_setprio(1);
#pragma unroll
        for (int cb = 0; cb < 4; ++cb) {
            sa[0][cb] = (f32x4){0.f, 0.f, 0.f, 0.f};
            sa[1][cb] = (f32x4){0.f, 0.f, 0.f, 0.f};
#pragma unroll
            for (int c = 0; c < 4; ++c) {
                const int rk = cb * 16 + l15;
                const f16x8 bk = *(const f16x8*)&KsB[rk * 128 + (((c * 4 + lq) ^ (rk & 7)) << 3)];
                sa[0][cb] = __builtin_amdgcn_mfma_f32_16x16x32_f16(bk, aq[0][c], sa[0][cb], 0, 0, 0);
                sa[1][cb] = __builtin_amdgcn_mfma_f32_16x16x32_f16(bk, aq[1][c], sa[1][cb], 0, 0, 0);
            }
        }
        __builtin_amdgcn_s_setprio(0);

#pragma unroll
        for (int rg = 0; rg < 2; ++rg) {
            float gm = sa[rg][0][0];
#pragma unroll
            for (int cb = 0; cb < 4; ++cb)
#pragma unroll
                for (int reg = 0; reg < 4; ++reg)
                    gm = fmaxf(gm, sa[rg][cb][reg]);
            gm = fmaxf(gm, __shfl_xor(gm, 16));
            gm = fmaxf(gm, __shfl_xor(gm, 32));
            if (__ballot(gm > m_q[rg] + 11.5f)) {
                const float mnew = fmaxf(m_q[rg], gm);
                const float alpha = __builtin_amdgcn_exp2f(m_q[rg] - mnew);
                m_q[rg] = mnew;
                l_q[rg] *= alpha;
                f32x4 av;
#pragma unroll
                for (int reg = 0; reg < 4; ++reg)
                    av[reg] = __shfl(alpha, lq * 4 + reg);
#pragma unroll
                for (int db = 0; db < 8; ++db) acc_o[rg][db] *= av;
            }
        }

        f16x4 va0 = tr16<0>(vtaB),    vb0 = tr16<512>(vtaB);
        f16x4 va1 = tr16<1024>(vtaB), vb1 = tr16<1536>(vtaB);
        f16x4 ca0 = tr16<2048>(vtaB), cb0 = tr16<2560>(vtaB);
        f16x4 ca1 = tr16<3072>(vtaB), cb1 = tr16<3584>(vtaB);

        f16x8 pa[2][2];
#pragma unroll
        for (int rg = 0; rg < 2; ++rg) {
            float ps = 0.f;
#pragma unroll
            for (int cb = 0; cb < 4; ++cb)
#pragma unroll
                for (int reg = 0; reg < 4; ++reg) {
                    const float p = __builtin_amdgcn_exp2f(sa[rg][cb][reg] - m_q[rg]);
                    sa[rg][cb][reg] = p;
                    ps += p;
                }
            l_q[rg] += ps;
#pragma unroll
            for (int kc = 0; kc < 2; ++kc) {
                union { h16x2 h2[4]; f16x8 h8; } u;
                u.h2[0] = __builtin_amdgcn_cvt_pkrtz(sa[rg][2 * kc][0], sa[rg][2 * kc][1]);
                u.h2[1] = __builtin_amdgcn_cvt_pkrtz(sa[rg][2 * kc][2], sa[rg][2 * kc][3]);
                u.h2[2] = __builtin_amdgcn_cvt_pkrtz(sa[rg][2 * kc + 1][0], sa[rg][2 * kc + 1][1]);
                u.h2[3] = __builtin_amdgcn_cvt_pkrtz(sa[rg][2 * kc + 1][2], sa[rg][2 * kc + 1][3]);
                pa[rg][kc] = u.h8;
            }
        }

        WAIT_LGKM(4);
        f16x8 v0 = SHUF8(va0, vb0), v1 = SHUF8(va1, vb1);
#pragma unroll
        for (int db = 0; db < 8; ++db) {
            f16x4 ma0, mb0, ma1, mb1;
            if (db < 6) {
                switch (db) {
                case 0: ma0=tr16<4096>(vtaB);  mb0=tr16<4608>(vtaB);  ma1=tr16<5120>(vtaB);  mb1=tr16<5632>(vtaB);  break;
                case 1: ma0=tr16<6144>(vtaB);  mb0=tr16<6656>(vtaB);  ma1=tr16<7168>(vtaB);  mb1=tr16<7680>(vtaB);  break;
                case 2: ma0=tr16<8192>(vtaB);  mb0=tr16<8704>(vtaB);  ma1=tr16<9216>(vtaB);  mb1=tr16<9728>(vtaB);  break;
                case 3: ma0=tr16<10240>(vtaB); mb0=tr16<10752>(vtaB); ma1=tr16<11264>(vtaB); mb1=tr16<11776>(vtaB); break;
                case 4: ma0=tr16<12288>(vtaB); mb0=tr16<12800>(vtaB); ma1=tr16<13312>(vtaB); mb1=tr16<13824>(vtaB); break;
                default:ma0=tr16<14336>(vtaB); mb0=tr16<14848>(vtaB); ma1=tr16<15360>(vtaB); mb1=tr16<15872>(vtaB); break;
                }
                WAIT_LGKM(4);
            } else if (db == 6) {
                WAIT_LGKM(0);
            }
            f16x8 n0, n1;
            if (db < 7) { n0 = SHUF8(ca0, cb0); n1 = SHUF8(ca1, cb1); }
            __builtin_amdgcn_s_setprio(1);
            acc_o[0][db] = __builtin_amdgcn_mfma_f32_16x16x32_f16(pa[0][0], v0, acc_o[0][db], 0, 0, 0);
            acc_o[1][db] = __builtin_amdgcn_mfma_f32_16x16x32_f16(pa[1][0], v0, acc_o[1][db], 0, 0, 0);
            acc_o[0][db] = __builtin_amdgcn_mfma_f32_16x16x32_f16(pa[0][1], v1, acc_o[0][db], 0, 0, 0);
            acc_o[1][db] = __builtin_amdgcn_mfma_f32_16x16x32_f16(pa[1][1], v1, acc_o[1][db], 0, 0, 0);
            __builtin_amdgcn_s_setprio(0);
            if (db < 7) {
                v0 = n0; v1 = n1;
                ca0 = ma0; cb0 = mb0; ca1 = ma1; cb1 = mb1;
            }
        }
    };

    issue_tile(0, 0);
#pragma unroll 1
    for (int t2 = 0; t2 < 16; ++t2) {
        const int kt0 = t2 << 1;
        issue_tile(1, kt0 + 1);
        WAIT_VM8();
        BAR();
        compute_tile(&KsA[0][0], vta0);
        BAR();
        if (t2 < 15) {
            issue_tile(0, kt0 + 2);
            WAIT_VM8();
        } else {
            WAIT_VM0();
        }
        BAR();
        compute_tile(&KsA[1][0], vta1);
        BAR();
    }

    const size_t obase = (size_t)(b * SEQ + q0 + w * 32) * D_MODEL + h * HD;
#pragma unroll
    for (int rg = 0; rg < 2; ++rg) {
        float lr = l_q[rg];
        lr += __shfl_xor(lr, 16);
        lr += __shfl_xor(lr, 32);
        float inv_l[4];
#pragma unroll
        for (int reg = 0; reg < 4; ++reg)
            inv_l[reg] = 1.f / __shfl(lr, lq * 4 + reg);
#pragma unroll
        for (int db = 0; db < 8; ++db) {
#pragma unroll
            for (int reg = 0; reg < 4; ++reg) {
                const size_t off = obase + (size_t)(rg * 16 + lq * 4 + reg) * D_MODEL + db * 16 + l15;
                const float v = acc_o[rg][db][reg] * inv_l[reg];
                const f16 hh = (f16)v;
                AOh[off] = hh;
                AOl[off] = (f16)(v - (float)hh);
            }
        }
    }
}

extern "C" void kernel_launch(void* const* d_in, const int* in_sizes, int n_in,
                              void* d_out, int out_size, void* d_ws, size_t ws_size,
                              hipStream_t stream)
{
    const float* x  = (const float*)d_in[0];
    const float* Wq = (const float*)d_in[1];
    const float* bq = (const float*)d_in[2];
    const float* Wk = (const float*)d_in[3];
    const float* bk = (const float*)d_in[4];
    const float* Wv = (const float*)d_in[5];
    const float* bv = (const float*)d_in[6];
    const float* Wo = (const float*)d_in[7];
    const float* bo = (const float*)d_in[8];
    float* out = (float*)d_out;

    // workspace (f16 units), total 41,943,040 f16 = 83.9 MB.
    // AOh/AOl alias xh/xl-slot (x dead after Q/KV GEMMs); Wo^T reuses Wq^T slot.
    // Prefetch over-reads (≤64 f16 past any array) stay inside d_ws.
    f16* base  = (f16*)d_ws;
    f16* xh    = base;                 // 8388608
    f16* xl    = base + 8388608;       // 8388608 (only used as AOl now)
    f16* WkvT  = base + 16777216;      // 2097152 (K rows 0..511, V rows 512..1023)
    f16* WqoT  = base + 20971520;      // 4194304 (Wq, later Wo)
    f16* Qp    = base + 29360128;      // 8388608
    f16* Kp    = base + 37748736;      // 2097152
    f16* Vp    = base + 39845888;      // 2097152 -> end 41943040
    f16* AOh   = xh;
    f16* AOl   = xl;

    const dim3 blk(256);
    // 1/sqrt(128) * log2(e): scores arrive in log2 units for exp2-direct softmax
    const float qscale = 0.08838834764831845f * 1.4426950408889634f;

    cast_f16<<<dim3(M_TOT * D_MODEL / 8 / 256), blk, 0, stream>>>(x, xh);
    transpose_cast<<<dim3(64, 64), blk, 0, stream>>>(Wq, WqoT, 2048, 2048, 0);
    transpose_cast<<<dim3(16, 64), blk, 0, stream>>>(Wk, WkvT, 2048, 512, 0);
    transpose_cast<<<dim3(16, 64), blk, 0, stream>>>(Wv, WkvT, 2048, 512, 512);

    // Q projection: 1-term f16 GEMM, qscale folded
    gemm_bk64<128, false, false><<<dim3(16, 32), blk, 0, stream>>>(
        xh, nullptr, WqoT, bq, bq, Qp, Qp, 2048, 2048, 2048, 2048, qscale);
    // K|V projection: 1-term f16 GEMM
    gemm_bk64<64, false, false><<<dim3(16, 32), blk, 0, stream>>>(
        xh, nullptr, WkvT, bk, bv, Kp, Vp, 512, 512, 512, 2048, 1.0f);

    // Wo^T into the (now dead) Wq^T slot, before attention overwrites xh/xl
    transpose_cast<<<dim3(64, 64), blk, 0, stream>>>(Wo, WqoT, 2048, 2048, 0);

    flash_attn_mfma<<<dim3(SEQ / 128, NQH, B_SZ), blk, 0, stream>>>(Qp, Kp, Vp, AOh, AOl);

    // O projection: 2-term (AOh+AOl) @ Wo^T, fp32 out
    gemm_bk64<128, true, true><<<dim3(16, 32), blk, 0, stream>>>(
        AOh, AOl, WqoT, bo, bo, out, out, 2048, 2048, 2048, 2048, 1.0f);
}

// Round 13
// 227.390 us; speedup vs baseline: 1.6539x; 1.1210x over previous
//
#include <hip/hip_runtime.h>

#define D_MODEL 2048
#define GHD 512        // NUM_KV_GROUPS * HEAD_DIM
#define HD 128
#define NQH 16
#define B_SZ 2
#define SEQ 2048
#define M_TOT (B_SZ * SEQ)   // 4096

typedef _Float16 f16;
typedef __fp16 h16x2 __attribute__((ext_vector_type(2)));   // cvt_pkrtz native type
typedef _Float16 f16x4 __attribute__((ext_vector_type(4)));
typedef _Float16 f16x8 __attribute__((ext_vector_type(8)));
typedef float f32x4 __attribute__((ext_vector_type(4)));

typedef const __attribute__((address_space(1))) void gvoid;
typedef __attribute__((address_space(3))) void lvoid;
typedef __attribute__((address_space(3))) f16 lf16;

// raw barrier (no vmcnt(0) drain) with compiler fences
#define BAR() do { asm volatile("" ::: "memory"); \
                   __builtin_amdgcn_s_barrier();  \
                   asm volatile("" ::: "memory"); } while (0)
#define WAIT_VM8() asm volatile("s_waitcnt vmcnt(8)" ::: "memory")
#define WAIT_VM0() asm volatile("s_waitcnt vmcnt(0)" ::: "memory")
#define WAIT_LGKM(N) do { asm volatile("s_waitcnt lgkmcnt(" #N ")" ::: "memory"); \
                          __builtin_amdgcn_sched_barrier(0); } while (0)

// hardware transpose read: with per-lane addr = base + l*8B, lane l elem j
// reads f16 at base_f16[OFF/2 + (l>>4)*64 + j*16 + (l&15)]
template<int OFF>
__device__ __forceinline__ f16x4 tr16(unsigned a) {
    f16x4 d;
    asm volatile("ds_read_b64_tr_b16 %0, %1 offset:%2"
                 : "=v"(d) : "v"(a), "i"(OFF));
    return d;
}

// ---------------------------------------------------------------------------
// x (fp32) -> f16 cast, elementwise
// ---------------------------------------------------------------------------
__global__ __launch_bounds__(256) void cast_f16(
    const float* __restrict__ X, f16* __restrict__ Xh)
{
    const size_t i = ((size_t)blockIdx.x * 256 + threadIdx.x) * 8;
    const float4 v0 = *(const float4*)(X + i);
    const float4 v1 = *(const float4*)(X + i + 4);
    f16x8 h;
    h[0] = (f16)v0.x; h[1] = (f16)v0.y; h[2] = (f16)v0.z; h[3] = (f16)v0.w;
    h[4] = (f16)v1.x; h[5] = (f16)v1.y; h[6] = (f16)v1.z; h[7] = (f16)v1.w;
    *(f16x8*)(Xh + i) = h;
}

// ---------------------------------------------------------------------------
// Transpose + f16 cast: W[K][N] fp32 -> Th[(row_off+n)][K] f16
// ---------------------------------------------------------------------------
__global__ __launch_bounds__(256) void transpose_cast(
    const float* __restrict__ W, f16* __restrict__ Th,
    int K, int N, int row_off)
{
    __shared__ float Ls[32][33];
    const int t = threadIdx.x;
    const int n0 = blockIdx.x << 5, k0 = blockIdx.y << 5;
    {
        const int kr = t >> 3, nq = (t & 7) << 2;
        const float4 v = *(const float4*)&W[(size_t)(k0 + kr) * N + n0 + nq];
        Ls[kr][nq + 0] = v.x; Ls[kr][nq + 1] = v.y;
        Ls[kr][nq + 2] = v.z; Ls[kr][nq + 3] = v.w;
    }
    __syncthreads();
    const int nr = t >> 3, kq = (t & 7) << 2;
    f16x4 hv;
#pragma unroll
    for (int e = 0; e < 4; ++e) hv[e] = (f16)Ls[kq + e][nr];
    *(f16x4*)&Th[(size_t)(row_off + n0 + nr) * K + k0 + kq] = hv;
}

// ---------------------------------------------------------------------------
// 1-term f16 MFMA GEMM, BK=64: C = Ah @ Bh^T + bias.
// BM=128, 256 threads (4 waves). LDK=72 pad (bank-uniform LDS ops).
// XCD-aware block swizzle (T1). Last-iter prefetch over-reads stay in d_ws.
// ---------------------------------------------------------------------------
template<int BN, bool OUT32>
__global__ __launch_bounds__(256) void gemm_bk64(
    const f16* __restrict__ Agh,
    const f16* __restrict__ BTh,
    const float* __restrict__ bias0, const float* __restrict__ bias1,
    void* __restrict__ C0v, void* __restrict__ C1v,
    int Nsplit, int ld0, int ld1, int K, float outscale)
{
    constexpr int WN = BN / 64;           // waves along n
    constexpr int WM = 4 / WN;            // waves along m
    constexpr int WI = 128 / (WM * 16);   // m-frags per wave
    constexpr int LDK = 72;               // padded row (f16)
    constexpr int NBP = BN / 32;          // B staging passes (4 or 2)

    __shared__ f16 Ah[128 * LDK];
    __shared__ f16 Bh[BN * LDK];

    const int tid = threadIdx.x;
    const int l = tid & 63, w = tid >> 6;
    const int l15 = l & 15, lq = l >> 4;
    const int wr = w / WN, wc = w % WN;

    // XCD swizzle: contiguous chunk of tiles per XCD (nwg = 512, div by 8)
    const int nwgx = gridDim.x;
    const int orig = blockIdx.y * nwgx + blockIdx.x;
    const int cpx = (nwgx * gridDim.y) >> 3;
    const int sw = (orig & 7) * cpx + (orig >> 3);
    const int m0 = (sw / nwgx) << 7;
    const int n0 = (sw % nwgx) * BN;

    f32x4 acc[WI][4];
#pragma unroll
    for (int i = 0; i < WI; ++i)
#pragma unroll
        for (int j = 0; j < 4; ++j) acc[i][j] = (f32x4){0.f, 0.f, 0.f, 0.f};

    const int srow = tid >> 3;            // 0..31
    const int skc  = (tid & 7) << 3;      // 0,8,..,56 (f16)
    const f16* Ap = Agh + (size_t)(m0 + srow) * K + skc;
    const f16* Bp = BTh + (size_t)(n0 + srow) * K + skc;

    f16x8 av[4], bv[NBP];
#pragma unroll
    for (int p = 0; p < 4; ++p)
        av[p] = *(const f16x8*)(Ap + (size_t)(p * 32) * K);
#pragma unroll
    for (int p = 0; p < NBP; ++p)
        bv[p] = *(const f16x8*)(Bp + (size_t)(p * 32) * K);

    for (int k0 = 0; k0 < K; k0 += 64) {
        __syncthreads();   // previous iteration's fragment reads done
#pragma unroll
        for (int p = 0; p < 4; ++p)
            *(f16x8*)&Ah[(srow + p * 32) * LDK + skc] = av[p];
#pragma unroll
        for (int p = 0; p < NBP; ++p)
            *(f16x8*)&Bh[(srow + p * 32) * LDK + skc] = bv[p];
        __syncthreads();

        // prefetch next k0 (flies under MFMA; last-iter over-read stays in ws)
        const int kn = k0 + 64;
#pragma unroll
        for (int p = 0; p < 4; ++p)
            av[p] = *(const f16x8*)(Ap + (size_t)(p * 32) * K + kn);
#pragma unroll
        for (int p = 0; p < NBP; ++p)
            bv[p] = *(const f16x8*)(Bp + (size_t)(p * 32) * K + kn);

#pragma unroll
        for (int c = 0; c < 2; ++c) {
            f16x8 afh[WI];
#pragma unroll
            for (int i = 0; i < WI; ++i) {
                const int row = wr * (WI * 16) + i * 16 + l15;
                afh[i] = *(const f16x8*)&Ah[row * LDK + c * 32 + lq * 8];
            }
#pragma unroll
            for (int j = 0; j < 4; ++j) {
                const int bn = wc * 64 + j * 16 + l15;
                const f16x8 bfh = *(const f16x8*)&Bh[bn * LDK + c * 32 + lq * 8];
#pragma unroll
                for (int i = 0; i < WI; ++i)
                    acc[i][j] = __builtin_amdgcn_mfma_f32_16x16x32_f16(afh[i], bfh, acc[i][j], 0, 0, 0);
            }
        }
    }

#pragma unroll
    for (int j = 0; j < 4; ++j) {
        const int ng = n0 + wc * 64 + j * 16 + l15;
        const bool first = ng < Nsplit;
        const float bvf = first ? bias0[ng] : bias1[ng - Nsplit];
        const int nc = first ? ng : ng - Nsplit;
        const int ldc = first ? ld0 : ld1;
#pragma unroll
        for (int i = 0; i < WI; ++i) {
            const int mg = m0 + wr * (WI * 16) + i * 16 + lq * 4;
#pragma unroll
            for (int r = 0; r < 4; ++r) {
                const float v = (acc[i][j][r] + bvf) * outscale;
                if (OUT32)
                    ((float*)(first ? C0v : C1v))[(size_t)(mg + r) * ldc + nc] = v;
                else
                    ((f16*)(first ? C0v : C1v))[(size_t)(mg + r) * ldc + nc] = (f16)v;
            }
        }
    }
}

#define SHUF8(x, y) __builtin_shufflevector(x, y, 0, 1, 2, 3, 4, 5, 6, 7)

// ---------------------------------------------------------------------------
// fp16-MFMA flash attention v6.1: as round 12 (passed), but AO output is
// single f16 (no hi/lo split) — the O-GEMM is 1-term now; epilogue stores
// halve. 4 waves x 32 q-rows, swapped QK^T (in-register P via cvt_pkrtz,
// zero P LDS), permuted V tr16 subtiles, per-q ballot-deferred softmax,
// double-buffered K/V via global_load_lds + counted vmcnt + raw barriers.
// ---------------------------------------------------------------------------
__global__ __launch_bounds__(256, 2) void flash_attn_mfma(
    const f16* __restrict__ Q, const f16* __restrict__ Kp,
    const f16* __restrict__ Vp, f16* __restrict__ AOh)
{
    __shared__ f16 KsA[2][64 * 128];   // 32 KB
    __shared__ f16 VtA[2][64 * 128];   // 32 KB (tr16 subtiled, permuted rows)

    const int tid = threadIdx.x;
    const int w = tid >> 6, l = tid & 63;
    const int l15 = l & 15, lq = l >> 4;
    const int b = blockIdx.z, h = blockIdx.y, g = h >> 2;
    const int q0 = blockIdx.x << 7;    // 128 q-rows per block

    const f16* Qb = Q + (size_t)(b * SEQ + q0) * D_MODEL + h * HD;
    const f16* Kb = Kp + (size_t)b * SEQ * GHD + g * HD;
    const f16* Vb = Vp + (size_t)b * SEQ * GHD + g * HD;

    f16x8 aq[2][4];
#pragma unroll
    for (int rg = 0; rg < 2; ++rg) {
        const f16* qrow = Qb + (size_t)(w * 32 + rg * 16 + l15) * D_MODEL;
#pragma unroll
        for (int c = 0; c < 4; ++c)
            aq[rg][c] = *(const f16x8*)(qrow + c * 32 + lq * 8);
    }

    lf16* Ks3 = (lf16*)&KsA[0][0];
    lf16* Vt3 = (lf16*)&VtA[0][0];
    const f16* ksrc[4]; lf16* kdst[4];
    const f16* vsrc[4]; lf16* vdst[4];
#pragma unroll
    for (int i = 0; i < 4; ++i) {
        const int s = tid + (i << 8);
        {
            const int row = s >> 4, ul = s & 15;
            ksrc[i] = Kb + (size_t)row * GHD + ((ul ^ (row & 7)) << 3);
            kdst[i] = Ks3 + s * 8;
        }
        {
            const int dbit = s & 1, kvlo = (s >> 1) & 3, vlq = (s >> 3) & 3;
            const int jh = (s >> 5) & 1, kc = (s >> 6) & 1, dsub = s >> 7;
            const int kv = (kc << 5) | (jh << 4) | (vlq << 2) | kvlo;
            vsrc[i] = Vb + (size_t)kv * GHD + ((dsub << 4) | (dbit << 3));
            vdst[i] = Vt3 + s * 8;
        }
    }
    const unsigned vta0 = (unsigned)(size_t)(Vt3 + l * 4);
    const unsigned vta1 = vta0 + 16384;

    f32x4 acc_o[2][8];
#pragma unroll
    for (int rg = 0; rg < 2; ++rg)
#pragma unroll
        for (int i = 0; i < 8; ++i) acc_o[rg][i] = (f32x4){0.f, 0.f, 0.f, 0.f};
    float m_q[2] = {-1e30f, -1e30f};
    float l_q[2] = {0.f, 0.f};

    auto issue_tile = [&](int buf, int tile) {
        const size_t koff = (size_t)tile * 64 * GHD;
        const int KO = buf << 13;
#pragma unroll
        for (int i = 0; i < 4; ++i)
            __builtin_amdgcn_global_load_lds((gvoid*)(ksrc[i] + koff),
                                             (lvoid*)(kdst[i] + KO), 16, 0, 0);
#pragma unroll
        for (int i = 0; i < 4; ++i)
            __builtin_amdgcn_global_load_lds((gvoid*)(vsrc[i] + koff),
                                             (lvoid*)(vdst[i] + KO), 16, 0, 0);
    };

    auto compute_tile = [&](const f16* KsB, unsigned vtaB) {
        f32x4 sa[2][4];
        __builtin_amdgcn_s_setprio(1);
#pragma unroll
        for (int cb = 0; cb < 4; ++cb) {
            sa[0][cb] = (f32x4){0.f, 0.f, 0.f, 0.f};
            sa[1][cb] = (f32x4){0.f, 0.f, 0.f, 0.f};
#pragma unroll
            for (int c = 0; c < 4; ++c) {
                const int rk = cb * 16 + l15;
                const f16x8 bk = *(const f16x8*)&KsB[rk * 128 + (((c * 4 + lq) ^ (rk & 7)) << 3)];
                sa[0][cb] = __builtin_amdgcn_mfma_f32_16x16x32_f16(bk, aq[0][c], sa[0][cb], 0, 0, 0);
                sa[1][cb] = __builtin_amdgcn_mfma_f32_16x16x32_f16(bk, aq[1][c], sa[1][cb], 0, 0, 0);
            }
        }
        __builtin_amdgcn_s_setprio(0);

#pragma unroll
        for (int rg = 0; rg < 2; ++rg) {
            float gm = sa[rg][0][0];
#pragma unroll
            for (int cb = 0; cb < 4; ++cb)
#pragma unroll
                for (int reg = 0; reg < 4; ++reg)
                    gm = fmaxf(gm, sa[rg][cb][reg]);
            gm = fmaxf(gm, __shfl_xor(gm, 16));
            gm = fmaxf(gm, __shfl_xor(gm, 32));
            if (__ballot(gm > m_q[rg] + 11.5f)) {
                const float mnew = fmaxf(m_q[rg], gm);
                const float alpha = __builtin_amdgcn_exp2f(m_q[rg] - mnew);
                m_q[rg] = mnew;
                l_q[rg] *= alpha;
                f32x4 av;
#pragma unroll
                for (int reg = 0; reg < 4; ++reg)
                    av[reg] = __shfl(alpha, lq * 4 + reg);
#pragma unroll
                for (int db = 0; db < 8; ++db) acc_o[rg][db] *= av;
            }
        }

        f16x4 va0 = tr16<0>(vtaB),    vb0 = tr16<512>(vtaB);
        f16x4 va1 = tr16<1024>(vtaB), vb1 = tr16<1536>(vtaB);
        f16x4 ca0 = tr16<2048>(vtaB), cb0 = tr16<2560>(vtaB);
        f16x4 ca1 = tr16<3072>(vtaB), cb1 = tr16<3584>(vtaB);

        f16x8 pa[2][2];
#pragma unroll
        for (int rg = 0; rg < 2; ++rg) {
            float ps = 0.f;
#pragma unroll
            for (int cb = 0; cb < 4; ++cb)
#pragma unroll
                for (int reg = 0; reg < 4; ++reg) {
                    const float p = __builtin_amdgcn_exp2f(sa[rg][cb][reg] - m_q[rg]);
                    sa[rg][cb][reg] = p;
                    ps += p;
                }
            l_q[rg] += ps;
#pragma unroll
            for (int kc = 0; kc < 2; ++kc) {
                union { h16x2 h2[4]; f16x8 h8; } u;
                u.h2[0] = __builtin_amdgcn_cvt_pkrtz(sa[rg][2 * kc][0], sa[rg][2 * kc][1]);
                u.h2[1] = __builtin_amdgcn_cvt_pkrtz(sa[rg][2 * kc][2], sa[rg][2 * kc][3]);
                u.h2[2] = __builtin_amdgcn_cvt_pkrtz(sa[rg][2 * kc + 1][0], sa[rg][2 * kc + 1][1]);
                u.h2[3] = __builtin_amdgcn_cvt_pkrtz(sa[rg][2 * kc + 1][2], sa[rg][2 * kc + 1][3]);
                pa[rg][kc] = u.h8;
            }
        }

        WAIT_LGKM(4);
        f16x8 v0 = SHUF8(va0, vb0), v1 = SHUF8(va1, vb1);
#pragma unroll
        for (int db = 0; db < 8; ++db) {
            f16x4 ma0, mb0, ma1, mb1;
            if (db < 6) {
                switch (db) {
                case 0: ma0=tr16<4096>(vtaB);  mb0=tr16<4608>(vtaB);  ma1=tr16<5120>(vtaB);  mb1=tr16<5632>(vtaB);  break;
                case 1: ma0=tr16<6144>(vtaB);  mb0=tr16<6656>(vtaB);  ma1=tr16<7168>(vtaB);  mb1=tr16<7680>(vtaB);  break;
                case 2: ma0=tr16<8192>(vtaB);  mb0=tr16<8704>(vtaB);  ma1=tr16<9216>(vtaB);  mb1=tr16<9728>(vtaB);  break;
                case 3: ma0=tr16<10240>(vtaB); mb0=tr16<10752>(vtaB); ma1=tr16<11264>(vtaB); mb1=tr16<11776>(vtaB); break;
                case 4: ma0=tr16<12288>(vtaB); mb0=tr16<12800>(vtaB); ma1=tr16<13312>(vtaB); mb1=tr16<13824>(vtaB); break;
                default:ma0=tr16<14336>(vtaB); mb0=tr16<14848>(vtaB); ma1=tr16<15360>(vtaB); mb1=tr16<15872>(vtaB); break;
                }
                WAIT_LGKM(4);
            } else if (db == 6) {
                WAIT_LGKM(0);
            }
            f16x8 n0, n1;
            if (db < 7) { n0 = SHUF8(ca0, cb0); n1 = SHUF8(ca1, cb1); }
            __builtin_amdgcn_s_setprio(1);
            acc_o[0][db] = __builtin_amdgcn_mfma_f32_16x16x32_f16(pa[0][0], v0, acc_o[0][db], 0, 0, 0);
            acc_o[1][db] = __builtin_amdgcn_mfma_f32_16x16x32_f16(pa[1][0], v0, acc_o[1][db], 0, 0, 0);
            acc_o[0][db] = __builtin_amdgcn_mfma_f32_16x16x32_f16(pa[0][1], v1, acc_o[0][db], 0, 0, 0);
            acc_o[1][db] = __builtin_amdgcn_mfma_f32_16x16x32_f16(pa[1][1], v1, acc_o[1][db], 0, 0, 0);
            __builtin_amdgcn_s_setprio(0);
            if (db < 7) {
                v0 = n0; v1 = n1;
                ca0 = ma0; cb0 = mb0; ca1 = ma1; cb1 = mb1;
            }
        }
    };

    issue_tile(0, 0);
#pragma unroll 1
    for (int t2 = 0; t2 < 16; ++t2) {
        const int kt0 = t2 << 1;
        issue_tile(1, kt0 + 1);
        WAIT_VM8();
        BAR();
        compute_tile(&KsA[0][0], vta0);
        BAR();
        if (t2 < 15) {
            issue_tile(0, kt0 + 2);
            WAIT_VM8();
        } else {
            WAIT_VM0();
        }
        BAR();
        compute_tile(&KsA[1][0], vta1);
        BAR();
    }

    const size_t obase = (size_t)(b * SEQ + q0 + w * 32) * D_MODEL + h * HD;
#pragma unroll
    for (int rg = 0; rg < 2; ++rg) {
        float lr = l_q[rg];
        lr += __shfl_xor(lr, 16);
        lr += __shfl_xor(lr, 32);
        float inv_l[4];
#pragma unroll
        for (int reg = 0; reg < 4; ++reg)
            inv_l[reg] = 1.f / __shfl(lr, lq * 4 + reg);
#pragma unroll
        for (int db = 0; db < 8; ++db) {
#pragma unroll
            for (int reg = 0; reg < 4; ++reg) {
                const size_t off = obase + (size_t)(rg * 16 + lq * 4 + reg) * D_MODEL + db * 16 + l15;
                AOh[off] = (f16)(acc_o[rg][db][reg] * inv_l[reg]);
            }
        }
    }
}

extern "C" void kernel_launch(void* const* d_in, const int* in_sizes, int n_in,
                              void* d_out, int out_size, void* d_ws, size_t ws_size,
                              hipStream_t stream)
{
    const float* x  = (const float*)d_in[0];
    const float* Wq = (const float*)d_in[1];
    const float* bq = (const float*)d_in[2];
    const float* Wk = (const float*)d_in[3];
    const float* bk = (const float*)d_in[4];
    const float* Wv = (const float*)d_in[5];
    const float* bv = (const float*)d_in[6];
    const float* Wo = (const float*)d_in[7];
    const float* bo = (const float*)d_in[8];
    float* out = (float*)d_out;

    // workspace (f16 units), total 41,943,040 f16 = 83.9 MB.
    // AOh aliases xh (x dead after Q/KV GEMMs); Wo^T reuses Wq^T slot.
    // Prefetch over-reads (<=64 f16 past any array) stay inside d_ws.
    f16* base  = (f16*)d_ws;
    f16* xh    = base;                 // 8388608
    // [8388608, 16777216): slack (former xl)
    f16* WkvT  = base + 16777216;      // 2097152 (K rows 0..511, V rows 512..1023)
    f16* WqoT  = base + 20971520;      // 4194304 (Wq, later Wo)
    f16* Qp    = base + 29360128;      // 8388608
    f16* Kp    = base + 37748736;      // 2097152
    f16* Vp    = base + 39845888;      // 2097152 -> end 41943040
    f16* AOh   = xh;

    const dim3 blk(256);
    // 1/sqrt(128) * log2(e): scores arrive in log2 units for exp2-direct softmax
    const float qscale = 0.08838834764831845f * 1.4426950408889634f;

    cast_f16<<<dim3(M_TOT * D_MODEL / 8 / 256), blk, 0, stream>>>(x, xh);
    transpose_cast<<<dim3(64, 64), blk, 0, stream>>>(Wq, WqoT, 2048, 2048, 0);
    transpose_cast<<<dim3(16, 64), blk, 0, stream>>>(Wk, WkvT, 2048, 512, 0);
    transpose_cast<<<dim3(16, 64), blk, 0, stream>>>(Wv, WkvT, 2048, 512, 512);

    // Q projection: 1-term f16 GEMM, qscale folded
    gemm_bk64<128, false><<<dim3(16, 32), blk, 0, stream>>>(
        xh, WqoT, bq, bq, Qp, Qp, 2048, 2048, 2048, 2048, qscale);
    // K|V projection: 1-term f16 GEMM
    gemm_bk64<64, false><<<dim3(16, 32), blk, 0, stream>>>(
        xh, WkvT, bk, bv, Kp, Vp, 512, 512, 512, 2048, 1.0f);

    // Wo^T into the (now dead) Wq^T slot, before attention overwrites xh
    transpose_cast<<<dim3(64, 64), blk, 0, stream>>>(Wo, WqoT, 2048, 2048, 0);

    flash_attn_mfma<<<dim3(SEQ / 128, NQH, B_SZ), blk, 0, stream>>>(Qp, Kp, Vp, AOh);

    // O projection: 1-term f16 GEMM, fp32 out
    gemm_bk64<128, true><<<dim3(16, 32), blk, 0, stream>>>(
        AOh, WqoT, bo, bo, out, out, 2048, 2048, 2048, 2048, 1.0f);
}